// Round 1
// baseline (4733.658 us; speedup 1.0000x reference)
//
#include <hip/hip_runtime.h>
#include <math.h>

#define NWG 64
#define BDIM 256

constexpr int Bn = 32, Tn = 64, Hn = 320, Jn = 320, Vn = 1024, Sn = 128;
constexpr int G4n = 1280, VP1 = 1025;
constexpr int LSTR = 324;   // padded LDS row stride (floats): 16B-aligned rows, bank-spread

// workspace layout (float units)
constexpr int OFF_XP   = 0;                      // 32*64*320
constexpr int OFF_G    = OFF_XP + Bn*Tn*Jn;      // 1024*1280
constexpr int OFF_H    = OFF_G + Vn*G4n;         // 32*320
constexpr int OFF_C    = OFF_H + Bn*Hn;          // 2 * 32*320 (ping-pong)
constexpr int OFF_F    = OFF_C + 2*Bn*Hn;        // 32*320
constexpr int OFF_GPRE = OFF_F + Bn*Jn;          // 32*1280
constexpr int OFF_PMAX = OFF_GPRE + Bn*G4n;      // 32*64
constexpr int OFF_PIDX = OFF_PMAX + Bn*NWG;      // 32*64 (int)
constexpr int OFF_TIME = OFF_PIDX + Bn*NWG;      // 2*32 (int)
constexpr int OFF_SYM  = OFF_TIME + 64;          // 2*32 (int)
constexpr int OFF_BAR  = OFF_SYM + 64;           // 512 ints barrier area
constexpr int LDS_FLOATS = (17 + 20 + 32 + 32) * LSTR + 4 * Hn;  // 34004 -> 136016 B

__device__ __forceinline__ float sigmf(float x) { return 1.0f / (1.0f + expf(-x)); }

// ---------------- tree barrier over NWG workgroups ----------------
__device__ __forceinline__ void gbar(int* bar) {
    __syncthreads();
    if (threadIdx.x == 0) {
        __threadfence();
        int* gen = bar + 288;
        int g = __hip_atomic_load(gen, __ATOMIC_RELAXED, __HIP_MEMORY_SCOPE_AGENT);
        int leaf = blockIdx.x & 7;
        int* lc = bar + leaf * 32;
        if (__hip_atomic_fetch_add(lc, 1, __ATOMIC_ACQ_REL, __HIP_MEMORY_SCOPE_AGENT) == 7) {
            __hip_atomic_store(lc, 0, __ATOMIC_RELAXED, __HIP_MEMORY_SCOPE_AGENT);
            int* rc = bar + 256;
            if (__hip_atomic_fetch_add(rc, 1, __ATOMIC_ACQ_REL, __HIP_MEMORY_SCOPE_AGENT) == 7) {
                __hip_atomic_store(rc, 0, __ATOMIC_RELAXED, __HIP_MEMORY_SCOPE_AGENT);
                __hip_atomic_store(gen, g + 1, __ATOMIC_RELEASE, __HIP_MEMORY_SCOPE_AGENT);
            } else {
                while (__hip_atomic_load(gen, __ATOMIC_RELAXED, __HIP_MEMORY_SCOPE_AGENT) == g)
                    __builtin_amdgcn_s_sleep(1);
            }
        } else {
            while (__hip_atomic_load(gen, __ATOMIC_RELAXED, __HIP_MEMORY_SCOPE_AGENT) == g)
                __builtin_amdgcn_s_sleep(1);
        }
        __threadfence();
    }
    __syncthreads();
}

// ---------------- generic tiled f32 GEMM: C = A@B + bias ----------------
__global__ __launch_bounds__(256) void gemm_bias(const float* __restrict__ A,
                                                 const float* __restrict__ Bm,
                                                 const float* __restrict__ bias,
                                                 float* __restrict__ C,
                                                 int M, int N, int K) {
    __shared__ float As[16][65];
    __shared__ float Bs[16][65];
    const int tx = threadIdx.x & 15, ty = threadIdx.x >> 4;
    const int n0 = blockIdx.x * 64, m0 = blockIdx.y * 64;
    float acc[4][4] = {};
    for (int k0 = 0; k0 < K; k0 += 16) {
        for (int i = threadIdx.x; i < 1024; i += 256) {
            int mm = i >> 4, kk = i & 15;
            As[kk][mm] = A[(m0 + mm) * K + k0 + kk];
            int kk2 = i >> 6, nn = i & 63;
            Bs[kk2][nn] = Bm[(k0 + kk2) * N + n0 + nn];
        }
        __syncthreads();
#pragma unroll
        for (int kk = 0; kk < 16; ++kk) {
            float av[4], bv[4];
#pragma unroll
            for (int r = 0; r < 4; ++r) { av[r] = As[kk][ty * 4 + r]; bv[r] = Bs[kk][tx * 4 + r]; }
#pragma unroll
            for (int i2 = 0; i2 < 4; ++i2)
#pragma unroll
                for (int j2 = 0; j2 < 4; ++j2) acc[i2][j2] += av[i2] * bv[j2];
        }
        __syncthreads();
    }
#pragma unroll
    for (int i2 = 0; i2 < 4; ++i2)
#pragma unroll
        for (int j2 = 0; j2 < 4; ++j2)
            C[(m0 + ty * 4 + i2) * N + n0 + tx * 4 + j2] = acc[i2][j2] + bias[n0 + tx * 4 + j2];
}

// ---------------- init: h0,c0,dec0,f0, time/sym ----------------
__global__ __launch_bounds__(320) void init_state(const float* __restrict__ b_lstm,
                                                  const float* __restrict__ W_pred,
                                                  const float* __restrict__ b_pred,
                                                  const float* __restrict__ xp,
                                                  float* __restrict__ hg, float* __restrict__ cb,
                                                  float* __restrict__ fg,
                                                  int* __restrict__ timeb, int* __restrict__ symb) {
    __shared__ float h0s[Hn];
    const int b = blockIdx.x, j = threadIdx.x;
    float bi = b_lstm[j], bg2 = b_lstm[2 * Hn + j], bo = b_lstm[3 * Hn + j];
    // c = 0 initially: c0 = sig(bf)*0 + sig(bi)*tanh(bg)
    float c0 = sigmf(bi) * tanhf(bg2);
    float h0 = sigmf(bo) * tanhf(c0);
    h0s[j] = h0;
    hg[b * Hn + j] = h0;
    cb[b * Hn + j] = c0;  // ping-pong buffer 0
    __syncthreads();
    float d = b_pred[j];
#pragma unroll 8
    for (int k = 0; k < Hn; ++k) d += h0s[k] * W_pred[k * Jn + j];
    float enc = xp[(b * Tn + 0) * Jn + j];
    float fv = enc + d;
    fg[b * Jn + j] = fv > 0.0f ? fv : 0.0f;
    if (b == 0 && j < 64) { timeb[j] = 0; symb[j] = 0; }
}

// ---------------- persistent decode kernel ----------------
__global__ __launch_bounds__(BDIM, 1) void rnnt_decode(
    const float* __restrict__ xp, const float* __restrict__ Gm,
    float* __restrict__ hg, float* __restrict__ cb, float* __restrict__ fg,
    float* __restrict__ gpre, float* __restrict__ pmaxT, int* __restrict__ pidxT,
    int* __restrict__ timeb, int* __restrict__ symb, int* __restrict__ bar,
    const float* __restrict__ W_out, const float* __restrict__ b_out,
    const float* __restrict__ W_hh, const float* __restrict__ W_pred,
    const float* __restrict__ b_pred, const int* __restrict__ out_len,
    float* __restrict__ out) {
    extern __shared__ float lds[];
    float* WoutT = lds;                  // 17*LSTR  (this WG's W_out columns, transposed)
    float* WhhT  = WoutT + 17 * LSTR;    // 20*LSTR  (this WG's W_hh gate columns, transposed)
    float* f_s   = WhhT + 20 * LSTR;     // 32*LSTR
    float* h_s   = f_s + 32 * LSTR;      // 32*LSTR
    float* h2_s  = h_s + 32 * LSTR;      // 4*320

    const int w = blockIdx.x, tid = threadIdx.x;
    const int vcnt = (w == NWG - 1) ? 17 : 16;
    const int vb = w * 16, gb = w * 20;

    // one-time: stage weight slices into LDS (transposed, padded rows)
    for (int j = tid; j < Hn; j += BDIM) {
        for (int vv = 0; vv < vcnt; ++vv) WoutT[vv * LSTR + j] = W_out[j * VP1 + vb + vv];
        for (int g2 = 0; g2 < 20; ++g2) WhhT[g2 * LSTR + j] = W_hh[j * G4n + gb + g2];
    }
    __syncthreads();

    const int bA = tid >> 3, kA = tid & 7;      // phase A: 8 threads per batch element
    const int waveB = tid >> 6, laneB = tid & 63;
    const int bg = w >> 3, js = w & 7;          // phase B: (b-group, j-slice)
    const int bB = bg * 4 + waveB;
    int lenacc = 0;

    const bool has2 = (kA == 0) && (vcnt == 17);
    const bool hasg2 = (kA < 4);

    for (int s = 0; s < Sn; ++s) {
        // ================= Phase A =================
        // stage f (logits input) and h (for h@W_hh) into LDS
        for (int i = tid; i < Bn * 80; i += BDIM) {
            int b = i / 80, q = i - b * 80;
            *(float4*)(f_s + b * LSTR + q * 4) = *(const float4*)(fg + b * Jn + q * 4);
            *(float4*)(h_s + b * LSTR + q * 4) = *(const float4*)(hg + b * Hn + q * 4);
        }
        __syncthreads();
        {
            float a0 = b_out[vb + kA], a1 = b_out[vb + kA + 8];
            float a2 = has2 ? b_out[vb + 16] : 0.0f;
            float g0 = 0.0f, g1 = 0.0f, g2a = 0.0f;
            const float* fr = f_s + bA * LSTR;
            const float* hr = h_s + bA * LSTR;
            const float* wv0 = WoutT + kA * LSTR;
            const float* wv1 = WoutT + (kA + 8) * LSTR;
            const float* wv2 = WoutT + 16 * LSTR;
            const float* wg0 = WhhT + kA * LSTR;
            const float* wg1 = WhhT + (kA + 8) * LSTR;
            const float* wg2 = WhhT + (kA + 16) * LSTR;
#pragma unroll 4
            for (int j = 0; j < Hn; j += 4) {
                float4 fv = *(const float4*)(fr + j);
                float4 hv = *(const float4*)(hr + j);
                float4 u;
                u = *(const float4*)(wv0 + j); a0 += fv.x * u.x + fv.y * u.y + fv.z * u.z + fv.w * u.w;
                u = *(const float4*)(wv1 + j); a1 += fv.x * u.x + fv.y * u.y + fv.z * u.z + fv.w * u.w;
                if (has2) { u = *(const float4*)(wv2 + j); a2 += fv.x * u.x + fv.y * u.y + fv.z * u.z + fv.w * u.w; }
                u = *(const float4*)(wg0 + j); g0 += hv.x * u.x + hv.y * u.y + hv.z * u.z + hv.w * u.w;
                u = *(const float4*)(wg1 + j); g1 += hv.x * u.x + hv.y * u.y + hv.z * u.z + hv.w * u.w;
                if (hasg2) { u = *(const float4*)(wg2 + j); g2a += hv.x * u.x + hv.y * u.y + hv.z * u.z + hv.w * u.w; }
            }
            gpre[bA * G4n + gb + kA] = g0;
            gpre[bA * G4n + gb + kA + 8] = g1;
            if (hasg2) gpre[bA * G4n + gb + kA + 16] = g2a;
            // per-thread argmax over its 2-3 v, then 8-lane segmented reduce
            float mval = a0; int midx = vb + kA;
            if (a1 > mval) { mval = a1; midx = vb + kA + 8; }
            if (has2 && a2 > mval) { mval = a2; midx = vb + 16; }
#pragma unroll
            for (int m = 1; m < 8; m <<= 1) {
                float ov = __shfl_xor(mval, m, 64);
                int oi = __shfl_xor(midx, m, 64);
                if (ov > mval || (ov == mval && oi < midx)) { mval = ov; midx = oi; }
            }
            if (kA == 0) { pmaxT[bA * NWG + w] = mval; pidxT[bA * NWG + w] = midx; }
        }
        gbar(bar);
        // ================= Phase B =================
        {
            const int p = s & 1;
            // full argmax: 64 partials for this wave's batch element
            float mv = pmaxT[bB * NWG + laneB];
            int mi = pidxT[bB * NWG + laneB];
#pragma unroll
            for (int m = 1; m < 64; m <<= 1) {
                float ov = __shfl_xor(mv, m, 64);
                int oi = __shfl_xor(mi, m, 64);
                if (ov > mv || (ov == mv && oi < mi)) { mv = ov; mi = oi; }
            }
            const int label = mi;
            const int told = timeb[p * 32 + bB], sold = symb[p * 32 + bB];
            const int ol = out_len[bB];
            const bool active = told < ol;
            const bool emit = active && (label != Vn);
            int sym2 = emit ? sold + 1 : 0;
            const bool force = emit && (sym2 >= 2);
            const bool advance = (active && !emit) || force;
            const int tnew = told + (advance ? 1 : 0);
            sym2 = advance ? 0 : sym2;
            if (js == 0 && laneB == 0) {
                out[s * Bn + bB] = emit ? (float)label : 1024.0f;
                out[Sn * Bn + s * Bn + bB] = active ? mv : 0.0f;
                out[2 * Sn * Bn + s * Bn + bB] = (float)told;
                timeb[(p ^ 1) * 32 + bB] = tnew;
                symb[(p ^ 1) * 32 + bB] = sym2;
                if (emit) lenacc++;
            }
            // LSTM elementwise (wave per b); h2 -> LDS; masked state writes by js==0
            const float* cold = cb + p * (Bn * Hn) + bB * Hn;
            float* cnew = cb + (p ^ 1) * (Bn * Hn) + bB * Hn;
            if (emit) {
                const float* gp = gpre + bB * G4n;
                const float* gE = Gm + label * G4n;
                float xi[5], xf[5], xg[5], xo[5], cv[5];
#pragma unroll
                for (int r = 0; r < 5; ++r) {
                    int g2 = laneB + r * 64;
                    xi[r] = gp[g2] + gE[g2];
                    xf[r] = gp[Hn + g2] + gE[Hn + g2];
                    xg[r] = gp[2 * Hn + g2] + gE[2 * Hn + g2];
                    xo[r] = gp[3 * Hn + g2] + gE[3 * Hn + g2];
                    cv[r] = cold[g2];
                }
#pragma unroll
                for (int r = 0; r < 5; ++r) {
                    int g2 = laneB + r * 64;
                    float c2 = sigmf(xf[r]) * cv[r] + sigmf(xi[r]) * tanhf(xg[r]);
                    float h2 = sigmf(xo[r]) * tanhf(c2);
                    h2_s[waveB * Hn + g2] = h2;
                    if (js == 0) { cnew[g2] = c2; hg[bB * Hn + g2] = h2; }
                }
            } else {
#pragma unroll
                for (int r = 0; r < 5; ++r) {
                    int g2 = laneB + r * 64;
                    h2_s[waveB * Hn + g2] = hg[bB * Hn + g2];
                    if (js == 0) cnew[g2] = cold[g2];
                }
            }
            __syncthreads();
            // dec slice + f = relu(enc_t(tnew) + dec) for next step
            if (laneB < 40) {
                const int jj = js * 40 + laneB;
                float d = b_pred[jj];
                const float* hh = h2_s + waveB * Hn;
#pragma unroll 8
                for (int kk = 0; kk < Hn; ++kk) d += hh[kk] * W_pred[kk * Jn + jj];
                const int tc = tnew < (Tn - 1) ? tnew : (Tn - 1);
                float enc = xp[(bB * Tn + tc) * Jn + jj];
                float fv = enc + d;
                fg[bB * Jn + jj] = fv > 0.0f ? fv : 0.0f;
            }
        }
        gbar(bar);
    }
    if (js == 0 && laneB == 0) out[3 * Sn * Bn + bB] = (float)lenacc;
}

extern "C" void kernel_launch(void* const* d_in, const int* in_sizes, int n_in,
                              void* d_out, int out_size, void* d_ws, size_t ws_size,
                              hipStream_t stream) {
    (void)in_sizes; (void)n_in; (void)out_size; (void)ws_size;
    const float* x      = (const float*)d_in[0];
    const int*   outlen = (const int*)d_in[1];
    const float* W_enc  = (const float*)d_in[2];
    const float* b_enc  = (const float*)d_in[3];
    const float* Emb    = (const float*)d_in[4];
    const float* W_ih   = (const float*)d_in[5];
    const float* W_hh   = (const float*)d_in[6];
    const float* b_lstm = (const float*)d_in[7];
    const float* W_pred = (const float*)d_in[8];
    const float* b_pred = (const float*)d_in[9];
    const float* W_out  = (const float*)d_in[10];
    const float* b_out  = (const float*)d_in[11];

    float* ws    = (float*)d_ws;
    float* xp    = ws + OFF_XP;
    float* Gm    = ws + OFF_G;
    float* hg    = ws + OFF_H;
    float* cbuf  = ws + OFF_C;
    float* fg    = ws + OFF_F;
    float* gpre  = ws + OFF_GPRE;
    float* pmaxT = ws + OFF_PMAX;
    int*   pidxT = (int*)(ws + OFF_PIDX);
    int*   timeb = (int*)(ws + OFF_TIME);
    int*   symb  = (int*)(ws + OFF_SYM);
    int*   bar   = (int*)(ws + OFF_BAR);

    hipMemsetAsync(bar, 0, 512 * sizeof(int), stream);

    // x_proj = x @ W_enc + b_enc   (2048 x 1024 @ 1024 x 320)
    gemm_bias<<<dim3(5, 32), 256, 0, stream>>>(x, W_enc, b_enc, xp, Bn * Tn, Jn, 1024);
    // G = Emb @ W_ih + b_lstm      (1024 x 320 @ 320 x 1280)
    gemm_bias<<<dim3(20, 16), 256, 0, stream>>>(Emb, W_ih, b_lstm, Gm, Vn, G4n, Hn);
    // initial state
    init_state<<<32, 320, 0, stream>>>(b_lstm, W_pred, b_pred, xp, hg, cbuf, fg, timeb, symb);

    hipFuncSetAttribute(reinterpret_cast<const void*>(rnnt_decode),
                        hipFuncAttributeMaxDynamicSharedMemorySize, LDS_FLOATS * 4);
    rnnt_decode<<<NWG, BDIM, LDS_FLOATS * 4, stream>>>(
        xp, Gm, hg, cbuf, fg, gpre, pmaxT, pidxT, timeb, symb, bar,
        W_out, b_out, W_hh, W_pred, b_pred, outlen, (float*)d_out);
}

// Round 2
// 4387.691 us; speedup vs baseline: 1.0788x; 1.0788x over previous
//
#include <hip/hip_runtime.h>
#include <math.h>

typedef unsigned long long ull;

#define NWG 64
#define BDIM 256

constexpr int Bn = 32, Tn = 64, Hn = 320, Jn = 320, Vn = 1024, Sn = 128;
constexpr int G4n = 1280, VP1 = 1025;
constexpr int LSTR = 324;   // padded LDS row stride (floats)

// workspace layout (float units)
constexpr int OFF_XP   = 0;                      // 32*64*320
constexpr int OFF_G    = OFF_XP + Bn*Tn*Jn;      // 1024*1280
constexpr int OFF_H    = OFF_G + Vn*G4n;         // 32*320
constexpr int OFF_C    = OFF_H + Bn*Hn;          // 2 * 32*320 (ping-pong)
constexpr int OFF_F    = OFF_C + 2*Bn*Hn;        // 32*320
constexpr int OFF_GPRE = OFF_F + Bn*Jn;          // 32*1280
constexpr int OFF_PA   = OFF_GPRE + Bn*G4n;      // 32*64 ull = 4096 floats
constexpr int OFF_TIME = OFF_PA + 4096;          // 2*32 int
constexpr int OFF_SYM  = OFF_TIME + 64;          // 2*32 int
constexpr int OFF_BAR  = OFF_SYM + 64;           // 512 ints
constexpr int OFF_WPT  = OFF_BAR + 512;          // 320*320 transposed W_pred
constexpr int LDS_FLOATS = (17 + 20 + 32 + 32) * LSTR + 4 * Hn;  // 34004 floats

// relaxed agent-scope atomics: per-access cache-bypass (sc0 sc1), NO fences,
// NO L2 invalidation -> read-only weights stay hot in L1/L2 across steps.
#define AL(p)    __hip_atomic_load((p), __ATOMIC_RELAXED, __HIP_MEMORY_SCOPE_AGENT)
#define AS(p, v) __hip_atomic_store((p), (v), __ATOMIC_RELAXED, __HIP_MEMORY_SCOPE_AGENT)

__device__ __forceinline__ float sigmf(float x) { return 1.0f / (1.0f + expf(-x)); }

// monotonic (value,idx) pack: bigger float -> bigger key; tie -> smaller idx wins
__device__ __forceinline__ ull pack_key(float v, int idx) {
    unsigned u = __float_as_uint(v);
    u = (u & 0x80000000u) ? ~u : (u | 0x80000000u);
    return ((ull)u << 32) | (unsigned)(0x7FFFFFFF - idx);
}
__device__ __forceinline__ float key_val(ull k) {
    unsigned u = (unsigned)(k >> 32);
    return __uint_as_float((u & 0x80000000u) ? (u & 0x7FFFFFFFu) : ~u);
}
__device__ __forceinline__ int key_idx(ull k) { return 0x7FFFFFFF - (int)(k & 0xFFFFFFFFu); }

// ---------------- fence-free tree barrier over NWG workgroups ----------------
__device__ __forceinline__ void gbar(int* bar) {
    __syncthreads();   // compiler drains vmcnt before s_barrier -> prior sc1 stores are at L3
    if (threadIdx.x == 0) {
        int* gen = bar + 288;
        int g = AL(gen);
        int* lc = bar + (blockIdx.x & 7) * 32;
        if (__hip_atomic_fetch_add(lc, 1, __ATOMIC_RELAXED, __HIP_MEMORY_SCOPE_AGENT) == 7) {
            AS(lc, 0);
            int* rc = bar + 256;
            if (__hip_atomic_fetch_add(rc, 1, __ATOMIC_RELAXED, __HIP_MEMORY_SCOPE_AGENT) == 7) {
                AS(rc, 0);
                AS(gen, g + 1);
            } else {
                while (AL(gen) == g) __builtin_amdgcn_s_sleep(1);
            }
        } else {
            while (AL(gen) == g) __builtin_amdgcn_s_sleep(1);
        }
    }
    __syncthreads();
}

// ---------------- generic tiled f32 GEMM: C = A@B + bias ----------------
__global__ __launch_bounds__(256) void gemm_bias(const float* __restrict__ A,
                                                 const float* __restrict__ Bm,
                                                 const float* __restrict__ bias,
                                                 float* __restrict__ C,
                                                 int M, int N, int K) {
    __shared__ float As[16][65];
    __shared__ float Bs[16][65];
    const int tx = threadIdx.x & 15, ty = threadIdx.x >> 4;
    const int n0 = blockIdx.x * 64, m0 = blockIdx.y * 64;
    float acc[4][4] = {};
    for (int k0 = 0; k0 < K; k0 += 16) {
        for (int i = threadIdx.x; i < 1024; i += 256) {
            int mm = i >> 4, kk = i & 15;
            As[kk][mm] = A[(m0 + mm) * K + k0 + kk];
            int kk2 = i >> 6, nn = i & 63;
            Bs[kk2][nn] = Bm[(k0 + kk2) * N + n0 + nn];
        }
        __syncthreads();
#pragma unroll
        for (int kk = 0; kk < 16; ++kk) {
            float av[4], bv[4];
#pragma unroll
            for (int r = 0; r < 4; ++r) { av[r] = As[kk][ty * 4 + r]; bv[r] = Bs[kk][tx * 4 + r]; }
#pragma unroll
            for (int i2 = 0; i2 < 4; ++i2)
#pragma unroll
                for (int j2 = 0; j2 < 4; ++j2) acc[i2][j2] += av[i2] * bv[j2];
        }
        __syncthreads();
    }
#pragma unroll
    for (int i2 = 0; i2 < 4; ++i2)
#pragma unroll
        for (int j2 = 0; j2 < 4; ++j2)
            C[(m0 + ty * 4 + i2) * N + n0 + tx * 4 + j2] = acc[i2][j2] + bias[n0 + tx * 4 + j2];
}

// ---------------- 320x320 transpose: WpT[j][k] = W_pred[k][j] ----------------
__global__ __launch_bounds__(256) void transpose_pred(const float* __restrict__ W,
                                                      float* __restrict__ WT) {
    __shared__ float t[32][33];
    const int bx = blockIdx.x % 10, by = blockIdx.x / 10;
    const int lx = threadIdx.x & 31, ly = threadIdx.x >> 5;
#pragma unroll
    for (int r = 0; r < 32; r += 8)
        t[ly + r][lx] = W[(by * 32 + ly + r) * 320 + bx * 32 + lx];
    __syncthreads();
#pragma unroll
    for (int r = 0; r < 32; r += 8)
        WT[(bx * 32 + ly + r) * 320 + by * 32 + lx] = t[lx][ly + r];
}

// ---------------- init: h0,c0,f0, time/sym ----------------
__global__ __launch_bounds__(320) void init_state(const float* __restrict__ b_lstm,
                                                  const float* __restrict__ W_pred,
                                                  const float* __restrict__ b_pred,
                                                  const float* __restrict__ xp,
                                                  float* __restrict__ hg, float* __restrict__ cb,
                                                  float* __restrict__ fg,
                                                  int* __restrict__ timeb, int* __restrict__ symb) {
    __shared__ float h0s[Hn];
    const int b = blockIdx.x, j = threadIdx.x;
    float bi = b_lstm[j], bg2 = b_lstm[2 * Hn + j], bo = b_lstm[3 * Hn + j];
    float c0 = sigmf(bi) * tanhf(bg2);
    float h0 = sigmf(bo) * tanhf(c0);
    h0s[j] = h0;
    hg[b * Hn + j] = h0;
    cb[b * Hn + j] = c0;
    __syncthreads();
    float d = b_pred[j];
#pragma unroll 8
    for (int k = 0; k < Hn; ++k) d += h0s[k] * W_pred[k * Jn + j];
    float enc = xp[(b * Tn + 0) * Jn + j];
    float fv = enc + d;
    fg[b * Jn + j] = fv > 0.0f ? fv : 0.0f;
    if (b == 0 && j < 64) { timeb[j] = 0; symb[j] = 0; }
}

// ---------------- persistent decode kernel ----------------
__global__ __launch_bounds__(BDIM, 1) void rnnt_decode(
    const float* __restrict__ xp, const float* __restrict__ Gm,
    float* __restrict__ hg, float* __restrict__ cb, float* __restrict__ fg,
    float* __restrict__ gpre, ull* __restrict__ paT,
    int* __restrict__ timeb, int* __restrict__ symb, int* __restrict__ bar,
    const float* __restrict__ W_out, const float* __restrict__ b_out,
    const float* __restrict__ W_hh, const float* __restrict__ WpT,
    const float* __restrict__ b_pred, const int* __restrict__ out_len,
    float* __restrict__ out) {
    extern __shared__ float lds[];
    float* WoutT = lds;                  // 17*LSTR
    float* WhhT  = WoutT + 17 * LSTR;    // 20*LSTR
    float* f_s   = WhhT + 20 * LSTR;     // 32*LSTR
    float* h_s   = f_s + 32 * LSTR;      // 32*LSTR
    float* h2_s  = h_s + 32 * LSTR;      // 4*320

    const int w = blockIdx.x, tid = threadIdx.x;
    const int vb = w * 16, gb = w * 20;

    // one-time LDS weight staging (plain cached loads)
    {
        const int vcnt = (w == NWG - 1) ? 17 : 16;
        for (int j = tid; j < Hn; j += BDIM) {
            for (int vv = 0; vv < vcnt; ++vv) WoutT[vv * LSTR + j] = W_out[j * VP1 + vb + vv];
            for (int g2 = 0; g2 < 20; ++g2) WhhT[g2 * LSTR + j] = W_hh[j * G4n + gb + g2];
        }
    }
    __syncthreads();

    const int bA = tid >> 3, kA = tid & 7;      // phase A roles
    const int waveB = tid >> 6, laneB = tid & 63;
    const int bg = w >> 3, js = w & 7;          // phase B roles
    const int bB = bg * 4 + waveB;
    int lenacc = 0;

    const bool has2 = (kA == 0) && (w == NWG - 1);
    const bool hasg2 = (kA < 4);
    const ull* fg8 = (const ull*)fg;
    const ull* hg8 = (const ull*)hg;

    for (int s = 0; s < Sn; ++s) {
        // ================= Phase A =================
        for (int i = tid; i < Bn * 160; i += BDIM) {
            int b = i / 160, q = i - b * 160;
            ull vf = AL(fg8 + b * 160 + q);
            ull vh = AL(hg8 + b * 160 + q);
            *(ull*)(f_s + b * LSTR + 2 * q) = vf;
            *(ull*)(h_s + b * LSTR + 2 * q) = vh;
        }
        __syncthreads();
        {
            float a0 = b_out[vb + kA], a1 = b_out[vb + kA + 8];
            float a2 = has2 ? b_out[Vn] : 0.0f;
            float g0 = 0.0f, g1 = 0.0f, g2a = 0.0f;
            const float* fr = f_s + bA * LSTR;
            const float* hr = h_s + bA * LSTR;
            const float* wv0 = WoutT + kA * LSTR;
            const float* wv1 = WoutT + (kA + 8) * LSTR;
            const float* wv2 = WoutT + 16 * LSTR;
            const float* wg0 = WhhT + (2 * kA) * LSTR;
            const float* wg1 = WhhT + (2 * kA + 1) * LSTR;
            const float* wg2 = WhhT + (16 + kA) * LSTR;
#pragma unroll 4
            for (int j = 0; j < Hn; j += 4) {
                float4 fv = *(const float4*)(fr + j);
                float4 hv = *(const float4*)(hr + j);
                float4 u;
                u = *(const float4*)(wv0 + j); a0 += fv.x * u.x + fv.y * u.y + fv.z * u.z + fv.w * u.w;
                u = *(const float4*)(wv1 + j); a1 += fv.x * u.x + fv.y * u.y + fv.z * u.z + fv.w * u.w;
                if (has2) { u = *(const float4*)(wv2 + j); a2 += fv.x * u.x + fv.y * u.y + fv.z * u.z + fv.w * u.w; }
                u = *(const float4*)(wg0 + j); g0 += hv.x * u.x + hv.y * u.y + hv.z * u.z + hv.w * u.w;
                u = *(const float4*)(wg1 + j); g1 += hv.x * u.x + hv.y * u.y + hv.z * u.z + hv.w * u.w;
                if (hasg2) { u = *(const float4*)(wg2 + j); g2a += hv.x * u.x + hv.y * u.y + hv.z * u.z + hv.w * u.w; }
            }
            // packed 8B gate store (cols gb+2kA, gb+2kA+1) + scalar extra
            union { float f2[2]; ull u8; } pk;
            pk.f2[0] = g0; pk.f2[1] = g1;
            AS((ull*)(gpre + bA * G4n + gb + 2 * kA), pk.u8);
            if (hasg2) AS(gpre + bA * G4n + gb + 16 + kA, g2a);
            // packed argmax partial: 8-lane segmented max-reduce
            ull key = pack_key(a0, vb + kA);
            ull k1 = pack_key(a1, vb + kA + 8);
            if (k1 > key) key = k1;
            if (has2) { ull k2 = pack_key(a2, Vn); if (k2 > key) key = k2; }
#pragma unroll
            for (int m = 1; m < 8; m <<= 1) {
                ull o = __shfl_xor(key, m, 64);
                if (o > key) key = o;
            }
            if (kA == 0) AS(paT + bA * NWG + w, key);
        }
        gbar(bar);
        // ================= Phase B =================
        {
            const int p = s & 1;
            ull key = AL(paT + bB * NWG + laneB);
#pragma unroll
            for (int m = 1; m < 64; m <<= 1) {
                ull o = __shfl_xor(key, m, 64);
                if (o > key) key = o;
            }
            const int label = key_idx(key);
            const float mv = key_val(key);
            const int told = AL(timeb + p * 32 + bB), sold = AL(symb + p * 32 + bB);
            const int ol = out_len[bB];
            const bool active = told < ol;
            const bool emit = active && (label != Vn);
            int sym2 = emit ? sold + 1 : 0;
            const bool force = emit && (sym2 >= 2);
            const bool advance = (active && !emit) || force;
            const int tnew = told + (advance ? 1 : 0);
            sym2 = advance ? 0 : sym2;
            if (js == 0 && laneB == 0) {
                out[s * Bn + bB] = emit ? (float)label : 1024.0f;
                out[Sn * Bn + s * Bn + bB] = active ? mv : 0.0f;
                out[2 * Sn * Bn + s * Bn + bB] = (float)told;
                AS(timeb + (p ^ 1) * 32 + bB, tnew);
                AS(symb + (p ^ 1) * 32 + bB, sym2);
                if (emit) lenacc++;
            }
            // LSTM elementwise (redundant per js; wave per b)
            float* cold = cb + p * (Bn * Hn) + bB * Hn;
            float* cnew = cb + (p ^ 1) * (Bn * Hn) + bB * Hn;
            if (emit) {
                const float* gp = gpre + bB * G4n;
                const float* gE = Gm + (size_t)label * G4n;
                float xi[5], xf[5], xg[5], xo[5], cv[5];
#pragma unroll
                for (int r = 0; r < 5; ++r) {
                    int g2 = laneB + r * 64;
                    xi[r] = AL(gp + g2) + gE[g2];
                    xf[r] = AL(gp + Hn + g2) + gE[Hn + g2];
                    xg[r] = AL(gp + 2 * Hn + g2) + gE[2 * Hn + g2];
                    xo[r] = AL(gp + 3 * Hn + g2) + gE[3 * Hn + g2];
                    cv[r] = AL(cold + g2);
                }
#pragma unroll
                for (int r = 0; r < 5; ++r) {
                    int g2 = laneB + r * 64;
                    float c2 = sigmf(xf[r]) * cv[r] + sigmf(xi[r]) * tanhf(xg[r]);
                    float h2 = sigmf(xo[r]) * tanhf(c2);
                    h2_s[waveB * Hn + g2] = h2;
                    if (js == 0) { AS(cnew + g2, c2); AS(hg + bB * Hn + g2, h2); }
                }
            } else {
#pragma unroll
                for (int r = 0; r < 5; ++r) {
                    int g2 = laneB + r * 64;
                    float cv = AL(cold + g2);
                    h2_s[waveB * Hn + g2] = AL(hg + bB * Hn + g2);
                    if (js == 0) AS(cnew + g2, cv);
                }
            }
            // dec slice + f = relu(enc_t(tnew) + dec); h2_s region is wave-private
            if (laneB < 40) {
                const int jj = js * 40 + laneB;
                const float4* wr = (const float4*)(WpT + (size_t)jj * Jn);
                const float4* hh4 = (const float4*)(h2_s + waveB * Hn);
                float4 dv = make_float4(0.f, 0.f, 0.f, 0.f);
#pragma unroll 10
                for (int kk = 0; kk < 80; ++kk) {
                    float4 wv = wr[kk];
                    float4 hv = hh4[kk];   // same addr all lanes -> LDS broadcast
                    dv.x += wv.x * hv.x; dv.y += wv.y * hv.y;
                    dv.z += wv.z * hv.z; dv.w += wv.w * hv.w;
                }
                float d = b_pred[jj] + dv.x + dv.y + dv.z + dv.w;
                const int tc = tnew < (Tn - 1) ? tnew : (Tn - 1);
                float enc = xp[(bB * Tn + tc) * Jn + jj];
                float fv = enc + d;
                AS(fg + bB * Jn + jj, fv > 0.0f ? fv : 0.0f);
            }
        }
        gbar(bar);
    }
    if (js == 0 && laneB == 0) out[3 * Sn * Bn + bB] = (float)lenacc;
}

extern "C" void kernel_launch(void* const* d_in, const int* in_sizes, int n_in,
                              void* d_out, int out_size, void* d_ws, size_t ws_size,
                              hipStream_t stream) {
    (void)in_sizes; (void)n_in; (void)out_size; (void)ws_size;
    const float* x      = (const float*)d_in[0];
    const int*   outlen = (const int*)d_in[1];
    const float* W_enc  = (const float*)d_in[2];
    const float* b_enc  = (const float*)d_in[3];
    const float* Emb    = (const float*)d_in[4];
    const float* W_ih   = (const float*)d_in[5];
    const float* W_hh   = (const float*)d_in[6];
    const float* b_lstm = (const float*)d_in[7];
    const float* W_pred = (const float*)d_in[8];
    const float* b_pred = (const float*)d_in[9];
    const float* W_out  = (const float*)d_in[10];
    const float* b_out  = (const float*)d_in[11];

    float* ws    = (float*)d_ws;
    float* xp    = ws + OFF_XP;
    float* Gm    = ws + OFF_G;
    float* hg    = ws + OFF_H;
    float* cbuf  = ws + OFF_C;
    float* fg    = ws + OFF_F;
    float* gpre  = ws + OFF_GPRE;
    ull*   paT   = (ull*)(ws + OFF_PA);
    int*   timeb = (int*)(ws + OFF_TIME);
    int*   symb  = (int*)(ws + OFF_SYM);
    int*   bar   = (int*)(ws + OFF_BAR);
    float* WpT   = ws + OFF_WPT;

    hipMemsetAsync(bar, 0, 512 * sizeof(int), stream);

    gemm_bias<<<dim3(5, 32), 256, 0, stream>>>(x, W_enc, b_enc, xp, Bn * Tn, Jn, 1024);
    gemm_bias<<<dim3(20, 16), 256, 0, stream>>>(Emb, W_ih, b_lstm, Gm, Vn, G4n, Hn);
    transpose_pred<<<100, 256, 0, stream>>>(W_pred, WpT);
    init_state<<<32, 320, 0, stream>>>(b_lstm, W_pred, b_pred, xp, hg, cbuf, fg, timeb, symb);

    hipFuncSetAttribute(reinterpret_cast<const void*>(rnnt_decode),
                        hipFuncAttributeMaxDynamicSharedMemorySize, LDS_FLOATS * 4);
    rnnt_decode<<<NWG, BDIM, LDS_FLOATS * 4, stream>>>(
        xp, Gm, hg, cbuf, fg, gpre, paT, timeb, symb, bar,
        W_out, b_out, W_hh, WpT, b_pred, outlen, (float*)d_out);
}

// Round 3
// 4330.370 us; speedup vs baseline: 1.0931x; 1.0132x over previous
//
#include <hip/hip_runtime.h>
#include <math.h>

typedef unsigned long long ull;

#define NWG 64
#define BDIM 256

constexpr int Bn = 32, Tn = 64, Hn = 320, Jn = 320, Vn = 1024, Sn = 128;
constexpr int G4n = 1280, VP1 = 1025;
constexpr int LSTR = 324;   // padded LDS row stride (floats)

// workspace layout (float units)
constexpr int OFF_XP   = 0;                      // 32*64*320
constexpr int OFF_G    = OFF_XP + Bn*Tn*Jn;      // 1024*1280
constexpr int OFF_H    = OFF_G + Vn*G4n;         // 32*320
constexpr int OFF_C    = OFF_H + Bn*Hn;          // 2 * 32*320 (ping-pong)
constexpr int OFF_F    = OFF_C + 2*Bn*Hn;        // 32*320
constexpr int OFF_GPRE = OFF_F + Bn*Jn;          // 32*1280
constexpr int OFF_PA   = OFF_GPRE + Bn*G4n;      // 32*64 ull = 4096 floats
constexpr int OFF_TIME = OFF_PA + 4096;          // 2*32 int
constexpr int OFF_SYM  = OFF_TIME + 64;          // 2*32 int
constexpr int OFF_BAR  = OFF_SYM + 64;           // 512 ints: 8 leaf lines + root line
constexpr int OFF_FLAG = OFF_BAR + 512;          // 64*32 ints: per-WG release flag lines
constexpr int OFF_WPT  = OFF_FLAG + 2048;        // 320*320 transposed W_pred
constexpr int LDS_FLOATS = (17 + 20 + 32 + 32) * LSTR + 4 * Hn;  // 34004 floats

// relaxed agent-scope atomics: per-access cache-bypass, NO fences
#define AL(p)    __hip_atomic_load((p), __ATOMIC_RELAXED, __HIP_MEMORY_SCOPE_AGENT)
#define AS(p, v) __hip_atomic_store((p), (v), __ATOMIC_RELAXED, __HIP_MEMORY_SCOPE_AGENT)

__device__ __forceinline__ float sigmf(float x) { return 1.0f / (1.0f + expf(-x)); }

// monotonic (value,idx) pack: bigger float -> bigger key; tie -> smaller idx wins
__device__ __forceinline__ ull pack_key(float v, int idx) {
    unsigned u = __float_as_uint(v);
    u = (u & 0x80000000u) ? ~u : (u | 0x80000000u);
    return ((ull)u << 32) | (unsigned)(0x7FFFFFFF - idx);
}
__device__ __forceinline__ float key_val(ull k) {
    unsigned u = (unsigned)(k >> 32);
    return __uint_as_float((u & 0x80000000u) ? (u & 0x7FFFFFFFu) : ~u);
}
__device__ __forceinline__ int key_idx(ull k) { return 0x7FFFFFFF - (int)(k & 0xFFFFFFFFu); }

// ---- barrier v3: monotonic epochs, tree arrival, per-WG-line release fan-out ----
// bar:   leaf counters at bar[leaf*32], root counter at bar[256]   (monotonic)
// flags: per-WG release words at flags[wg*32]                      (monotonic)
__device__ __forceinline__ void gbar(int* bar, int* flags, int epoch) {
    __syncthreads();   // drains vmcnt -> prior sc1 data stores are visible at L3
    if (threadIdx.x < 64) {
        const int lane = threadIdx.x;
        int rootwin = 0;
        if (lane == 0) {
            int* lc = bar + (blockIdx.x & 7) * 32;
            int old = __hip_atomic_fetch_add(lc, 1, __ATOMIC_RELAXED, __HIP_MEMORY_SCOPE_AGENT);
            if ((old & 7) == 7) {
                int* rc = bar + 256;
                int ro = __hip_atomic_fetch_add(rc, 1, __ATOMIC_RELAXED, __HIP_MEMORY_SCOPE_AGENT);
                if ((ro & 7) == 7) rootwin = 1;
            }
        }
        rootwin = __shfl(rootwin, 0, 64);
        if (rootwin) AS(flags + lane * 32, epoch);   // 64 lanes -> 64 distinct lines
        if (lane == 0) {
            while (AL(flags + blockIdx.x * 32) < epoch) __builtin_amdgcn_s_sleep(4);
        }
    }
    __syncthreads();
}

// ---------------- generic tiled f32 GEMM: C = A@B + bias ----------------
__global__ __launch_bounds__(256) void gemm_bias(const float* __restrict__ A,
                                                 const float* __restrict__ Bm,
                                                 const float* __restrict__ bias,
                                                 float* __restrict__ C,
                                                 int M, int N, int K) {
    __shared__ float As[16][65];
    __shared__ float Bs[16][65];
    const int tx = threadIdx.x & 15, ty = threadIdx.x >> 4;
    const int n0 = blockIdx.x * 64, m0 = blockIdx.y * 64;
    float acc[4][4] = {};
    for (int k0 = 0; k0 < K; k0 += 16) {
        for (int i = threadIdx.x; i < 1024; i += 256) {
            int mm = i >> 4, kk = i & 15;
            As[kk][mm] = A[(m0 + mm) * K + k0 + kk];
            int kk2 = i >> 6, nn = i & 63;
            Bs[kk2][nn] = Bm[(k0 + kk2) * N + n0 + nn];
        }
        __syncthreads();
#pragma unroll
        for (int kk = 0; kk < 16; ++kk) {
            float av[4], bv[4];
#pragma unroll
            for (int r = 0; r < 4; ++r) { av[r] = As[kk][ty * 4 + r]; bv[r] = Bs[kk][tx * 4 + r]; }
#pragma unroll
            for (int i2 = 0; i2 < 4; ++i2)
#pragma unroll
                for (int j2 = 0; j2 < 4; ++j2) acc[i2][j2] += av[i2] * bv[j2];
        }
        __syncthreads();
    }
#pragma unroll
    for (int i2 = 0; i2 < 4; ++i2)
#pragma unroll
        for (int j2 = 0; j2 < 4; ++j2)
            C[(m0 + ty * 4 + i2) * N + n0 + tx * 4 + j2] = acc[i2][j2] + bias[n0 + tx * 4 + j2];
}

// ---------------- 320x320 transpose: WpT[j][k] = W_pred[k][j] ----------------
__global__ __launch_bounds__(256) void transpose_pred(const float* __restrict__ W,
                                                      float* __restrict__ WT) {
    __shared__ float t[32][33];
    const int bx = blockIdx.x % 10, by = blockIdx.x / 10;
    const int lx = threadIdx.x & 31, ly = threadIdx.x >> 5;
#pragma unroll
    for (int r = 0; r < 32; r += 8)
        t[ly + r][lx] = W[(by * 32 + ly + r) * 320 + bx * 32 + lx];
    __syncthreads();
#pragma unroll
    for (int r = 0; r < 32; r += 8)
        WT[(bx * 32 + ly + r) * 320 + by * 32 + lx] = t[lx][ly + r];
}

// ---------------- init: h0,c0,f0, time/sym ----------------
__global__ __launch_bounds__(320) void init_state(const float* __restrict__ b_lstm,
                                                  const float* __restrict__ W_pred,
                                                  const float* __restrict__ b_pred,
                                                  const float* __restrict__ xp,
                                                  float* __restrict__ hg, float* __restrict__ cb,
                                                  float* __restrict__ fg,
                                                  int* __restrict__ timeb, int* __restrict__ symb) {
    __shared__ float h0s[Hn];
    const int b = blockIdx.x, j = threadIdx.x;
    float bi = b_lstm[j], bg2 = b_lstm[2 * Hn + j], bo = b_lstm[3 * Hn + j];
    float c0 = sigmf(bi) * tanhf(bg2);
    float h0 = sigmf(bo) * tanhf(c0);
    h0s[j] = h0;
    hg[b * Hn + j] = h0;
    cb[b * Hn + j] = c0;
    __syncthreads();
    float d = b_pred[j];
#pragma unroll 8
    for (int k = 0; k < Hn; ++k) d += h0s[k] * W_pred[k * Jn + j];
    float enc = xp[(b * Tn + 0) * Jn + j];
    float fv = enc + d;
    fg[b * Jn + j] = fv > 0.0f ? fv : 0.0f;
    if (b == 0 && j < 64) { timeb[j] = 0; symb[j] = 0; }
}

// ---------------- persistent decode kernel ----------------
__global__ __launch_bounds__(BDIM, 1) void rnnt_decode(
    const float* __restrict__ xp, const float* __restrict__ Gm,
    float* __restrict__ hg, float* __restrict__ cb, float* __restrict__ fg,
    float* __restrict__ gpre, ull* __restrict__ paT,
    int* __restrict__ timeb, int* __restrict__ symb, int* __restrict__ bar,
    int* __restrict__ flags,
    const float* __restrict__ W_out, const float* __restrict__ b_out,
    const float* __restrict__ W_hh, const float* __restrict__ WpT,
    const float* __restrict__ b_pred, const int* __restrict__ out_len,
    float* __restrict__ out) {
    extern __shared__ float lds[];
    float* WoutT = lds;                  // 17*LSTR
    float* WhhT  = WoutT + 17 * LSTR;    // 20*LSTR
    float* f_s   = WhhT + 20 * LSTR;     // 32*LSTR
    float* h_s   = f_s + 32 * LSTR;      // 32*LSTR
    float* h2_s  = h_s + 32 * LSTR;      // 4*320

    const int w = blockIdx.x, tid = threadIdx.x;
    const int vb = w * 16, gb = w * 20;

    {
        const int vcnt = (w == NWG - 1) ? 17 : 16;
        for (int j = tid; j < Hn; j += BDIM) {
            for (int vv = 0; vv < vcnt; ++vv) WoutT[vv * LSTR + j] = W_out[j * VP1 + vb + vv];
            for (int g2 = 0; g2 < 20; ++g2) WhhT[g2 * LSTR + j] = W_hh[j * G4n + gb + g2];
        }
    }
    __syncthreads();

    const int bA = tid >> 3, kA = tid & 7;      // phase A roles
    const int waveB = tid >> 6, laneB = tid & 63;
    const int bg = w >> 3, js = w & 7;          // phase B roles
    const int bB = bg * 4 + waveB;
    int lenacc = 0;

    const bool has2 = (kA == 0) && (w == NWG - 1);
    const bool hasg2 = (kA < 4);
    const ull* fg8 = (const ull*)fg;
    const ull* hg8 = (const ull*)hg;
    const int ol = out_len[bB];                 // constant: hoisted

    for (int s = 0; s < Sn; ++s) {
        // ================= Phase A =================
        for (int i = tid; i < Bn * 160; i += BDIM) {
            int b = i / 160, q = i - b * 160;
            ull vf = AL(fg8 + b * 160 + q);
            ull vh = AL(hg8 + b * 160 + q);
            *(ull*)(f_s + b * LSTR + 2 * q) = vf;
            *(ull*)(h_s + b * LSTR + 2 * q) = vh;
        }
        __syncthreads();
        {
            float a0 = b_out[vb + kA], a1 = b_out[vb + kA + 8];
            float a2 = has2 ? b_out[Vn] : 0.0f;
            float g0 = 0.0f, g1 = 0.0f, g2a = 0.0f;
            const float* fr = f_s + bA * LSTR;
            const float* hr = h_s + bA * LSTR;
            const float* wv0 = WoutT + kA * LSTR;
            const float* wv1 = WoutT + (kA + 8) * LSTR;
            const float* wv2 = WoutT + 16 * LSTR;
            const float* wg0 = WhhT + (2 * kA) * LSTR;
            const float* wg1 = WhhT + (2 * kA + 1) * LSTR;
            const float* wg2 = WhhT + (16 + kA) * LSTR;
#pragma unroll 4
            for (int j = 0; j < Hn; j += 4) {
                float4 fv = *(const float4*)(fr + j);
                float4 hv = *(const float4*)(hr + j);
                float4 u;
                u = *(const float4*)(wv0 + j); a0 += fv.x * u.x + fv.y * u.y + fv.z * u.z + fv.w * u.w;
                u = *(const float4*)(wv1 + j); a1 += fv.x * u.x + fv.y * u.y + fv.z * u.z + fv.w * u.w;
                if (has2) { u = *(const float4*)(wv2 + j); a2 += fv.x * u.x + fv.y * u.y + fv.z * u.z + fv.w * u.w; }
                u = *(const float4*)(wg0 + j); g0 += hv.x * u.x + hv.y * u.y + hv.z * u.z + hv.w * u.w;
                u = *(const float4*)(wg1 + j); g1 += hv.x * u.x + hv.y * u.y + hv.z * u.z + hv.w * u.w;
                if (hasg2) { u = *(const float4*)(wg2 + j); g2a += hv.x * u.x + hv.y * u.y + hv.z * u.z + hv.w * u.w; }
            }
            union { float f2[2]; ull u8; } pk;
            pk.f2[0] = g0; pk.f2[1] = g1;
            AS((ull*)(gpre + bA * G4n + gb + 2 * kA), pk.u8);
            if (hasg2) AS(gpre + bA * G4n + gb + 16 + kA, g2a);
            ull key = pack_key(a0, vb + kA);
            ull k1 = pack_key(a1, vb + kA + 8);
            if (k1 > key) key = k1;
            if (has2) { ull k2 = pack_key(a2, Vn); if (k2 > key) key = k2; }
#pragma unroll
            for (int m = 1; m < 8; m <<= 1) {
                ull o = __shfl_xor(key, m, 64);
                if (o > key) key = o;
            }
            if (kA == 0) AS(paT + bA * NWG + w, key);
        }
        gbar(bar, flags, 2 * s + 1);
        // ================= Phase B =================
        {
            const int p = s & 1;
            ull key = AL(paT + bB * NWG + laneB);
#pragma unroll
            for (int m = 1; m < 64; m <<= 1) {
                ull o = __shfl_xor(key, m, 64);
                if (o > key) key = o;
            }
            const int label = key_idx(key);
            const float mv = key_val(key);
            const int told = AL(timeb + p * 32 + bB), sold = AL(symb + p * 32 + bB);
            const bool active = told < ol;
            const bool emit = active && (label != Vn);
            int sym2 = emit ? sold + 1 : 0;
            const bool force = emit && (sym2 >= 2);
            const bool advance = (active && !emit) || force;
            const int tnew = told + (advance ? 1 : 0);
            sym2 = advance ? 0 : sym2;
            if (js == 0 && laneB == 0) {
                out[s * Bn + bB] = emit ? (float)label : 1024.0f;
                out[Sn * Bn + s * Bn + bB] = active ? mv : 0.0f;
                out[2 * Sn * Bn + s * Bn + bB] = (float)told;
                AS(timeb + (p ^ 1) * 32 + bB, tnew);
                AS(symb + (p ^ 1) * 32 + bB, sym2);
                if (emit) lenacc++;
            }
            float* cold = cb + p * (Bn * Hn) + bB * Hn;
            float* cnew = cb + (p ^ 1) * (Bn * Hn) + bB * Hn;
            if (emit) {
                const float* gp = gpre + bB * G4n;
                const float* gE = Gm + (size_t)label * G4n;
                float xi[5], xf[5], xg[5], xo[5], cv[5];
#pragma unroll
                for (int r = 0; r < 5; ++r) {
                    int g2 = laneB + r * 64;
                    xi[r] = AL(gp + g2) + gE[g2];
                    xf[r] = AL(gp + Hn + g2) + gE[Hn + g2];
                    xg[r] = AL(gp + 2 * Hn + g2) + gE[2 * Hn + g2];
                    xo[r] = AL(gp + 3 * Hn + g2) + gE[3 * Hn + g2];
                    cv[r] = AL(cold + g2);
                }
#pragma unroll
                for (int r = 0; r < 5; ++r) {
                    int g2 = laneB + r * 64;
                    float c2 = sigmf(xf[r]) * cv[r] + sigmf(xi[r]) * tanhf(xg[r]);
                    float h2 = sigmf(xo[r]) * tanhf(c2);
                    h2_s[waveB * Hn + g2] = h2;
                    if (js == 0) { AS(cnew + g2, c2); AS(hg + bB * Hn + g2, h2); }
                }
            } else {
#pragma unroll
                for (int r = 0; r < 5; ++r) {
                    int g2 = laneB + r * 64;
                    float cv = AL(cold + g2);
                    h2_s[waveB * Hn + g2] = AL(hg + bB * Hn + g2);
                    if (js == 0) AS(cnew + g2, cv);
                }
            }
            if (laneB < 40) {
                const int jj = js * 40 + laneB;
                const float4* wr = (const float4*)(WpT + (size_t)jj * Jn);
                const float4* hh4 = (const float4*)(h2_s + waveB * Hn);
                float4 dv = make_float4(0.f, 0.f, 0.f, 0.f);
#pragma unroll 10
                for (int kk = 0; kk < 80; ++kk) {
                    float4 wv = wr[kk];
                    float4 hv = hh4[kk];
                    dv.x += wv.x * hv.x; dv.y += wv.y * hv.y;
                    dv.z += wv.z * hv.z; dv.w += wv.w * hv.w;
                }
                float d = b_pred[jj] + dv.x + dv.y + dv.z + dv.w;
                const int tc = tnew < (Tn - 1) ? tnew : (Tn - 1);
                float enc = xp[(bB * Tn + tc) * Jn + jj];
                float fv = enc + d;
                AS(fg + bB * Jn + jj, fv > 0.0f ? fv : 0.0f);
            }
        }
        gbar(bar, flags, 2 * s + 2);
    }
    if (js == 0 && laneB == 0) out[3 * Sn * Bn + bB] = (float)lenacc;
}

extern "C" void kernel_launch(void* const* d_in, const int* in_sizes, int n_in,
                              void* d_out, int out_size, void* d_ws, size_t ws_size,
                              hipStream_t stream) {
    (void)in_sizes; (void)n_in; (void)out_size; (void)ws_size;
    const float* x      = (const float*)d_in[0];
    const int*   outlen = (const int*)d_in[1];
    const float* W_enc  = (const float*)d_in[2];
    const float* b_enc  = (const float*)d_in[3];
    const float* Emb    = (const float*)d_in[4];
    const float* W_ih   = (const float*)d_in[5];
    const float* W_hh   = (const float*)d_in[6];
    const float* b_lstm = (const float*)d_in[7];
    const float* W_pred = (const float*)d_in[8];
    const float* b_pred = (const float*)d_in[9];
    const float* W_out  = (const float*)d_in[10];
    const float* b_out  = (const float*)d_in[11];

    float* ws    = (float*)d_ws;
    float* xp    = ws + OFF_XP;
    float* Gm    = ws + OFF_G;
    float* hg    = ws + OFF_H;
    float* cbuf  = ws + OFF_C;
    float* fg    = ws + OFF_F;
    float* gpre  = ws + OFF_GPRE;
    ull*   paT   = (ull*)(ws + OFF_PA);
    int*   timeb = (int*)(ws + OFF_TIME);
    int*   symb  = (int*)(ws + OFF_SYM);
    int*   bar   = (int*)(ws + OFF_BAR);
    int*   flags = (int*)(ws + OFF_FLAG);
    float* WpT   = ws + OFF_WPT;

    hipMemsetAsync(bar, 0, (512 + 2048) * sizeof(int), stream);

    gemm_bias<<<dim3(5, 32), 256, 0, stream>>>(x, W_enc, b_enc, xp, Bn * Tn, Jn, 1024);
    gemm_bias<<<dim3(20, 16), 256, 0, stream>>>(Emb, W_ih, b_lstm, Gm, Vn, G4n, Hn);
    transpose_pred<<<100, 256, 0, stream>>>(W_pred, WpT);
    init_state<<<32, 320, 0, stream>>>(b_lstm, W_pred, b_pred, xp, hg, cbuf, fg, timeb, symb);

    hipFuncSetAttribute(reinterpret_cast<const void*>(rnnt_decode),
                        hipFuncAttributeMaxDynamicSharedMemorySize, LDS_FLOATS * 4);
    rnnt_decode<<<NWG, BDIM, LDS_FLOATS * 4, stream>>>(
        xp, Gm, hg, cbuf, fg, gpre, paT, timeb, symb, bar, flags,
        W_out, b_out, W_hh, WpT, b_pred, outlen, (float*)d_out);
}

// Round 4
// 3985.043 us; speedup vs baseline: 1.1879x; 1.0867x over previous
//
#include <hip/hip_runtime.h>
#include <math.h>

typedef unsigned long long ull;

constexpr int Bn = 32, Tn = 64, Hn = 320, Jn = 320, Vn = 1024, Sn = 128;
constexpr int G4n = 1280, VP1 = 1025, WOS = 1028;  // WOS: padded W_out row stride (16B-aligned float4 cols)

// workspace layout (float units)
constexpr int OFF_XP = 0;                   // 32*64*320
constexpr int OFF_G  = OFF_XP + Bn*Tn*Jn;   // 1024*1280
constexpr int OFF_WO = OFF_G + Vn*G4n;      // 320*1028

__device__ __forceinline__ float sigmf(float x) { return 1.0f / (1.0f + expf(-x)); }

// monotonic (value,idx) pack: bigger float -> bigger key; tie -> smaller idx wins
__device__ __forceinline__ ull pack_key(float v, int idx) {
    unsigned u = __float_as_uint(v);
    u = (u & 0x80000000u) ? ~u : (u | 0x80000000u);
    return ((ull)u << 32) | (unsigned)(0x7FFFFFFF - idx);
}
__device__ __forceinline__ float key_val(ull k) {
    unsigned u = (unsigned)(k >> 32);
    return __uint_as_float((u & 0x80000000u) ? (u & 0x7FFFFFFFu) : ~u);
}
__device__ __forceinline__ int key_idx(ull k) { return 0x7FFFFFFF - (int)(k & 0xFFFFFFFFu); }

// ---------------- generic tiled f32 GEMM: C = A@B + bias ----------------
__global__ __launch_bounds__(256) void gemm_bias(const float* __restrict__ A,
                                                 const float* __restrict__ Bm,
                                                 const float* __restrict__ bias,
                                                 float* __restrict__ C,
                                                 int M, int N, int K) {
    __shared__ float As[16][65];
    __shared__ float Bs[16][65];
    const int tx = threadIdx.x & 15, ty = threadIdx.x >> 4;
    const int n0 = blockIdx.x * 64, m0 = blockIdx.y * 64;
    float acc[4][4] = {};
    for (int k0 = 0; k0 < K; k0 += 16) {
        for (int i = threadIdx.x; i < 1024; i += 256) {
            int mm = i >> 4, kk = i & 15;
            As[kk][mm] = A[(m0 + mm) * K + k0 + kk];
            int kk2 = i >> 6, nn = i & 63;
            Bs[kk2][nn] = Bm[(k0 + kk2) * N + n0 + nn];
        }
        __syncthreads();
#pragma unroll
        for (int kk = 0; kk < 16; ++kk) {
            float av[4], bv[4];
#pragma unroll
            for (int r = 0; r < 4; ++r) { av[r] = As[kk][ty * 4 + r]; bv[r] = Bs[kk][tx * 4 + r]; }
#pragma unroll
            for (int i2 = 0; i2 < 4; ++i2)
#pragma unroll
                for (int j2 = 0; j2 < 4; ++j2) acc[i2][j2] += av[i2] * bv[j2];
        }
        __syncthreads();
    }
#pragma unroll
    for (int i2 = 0; i2 < 4; ++i2)
#pragma unroll
        for (int j2 = 0; j2 < 4; ++j2)
            C[(m0 + ty * 4 + i2) * N + n0 + tx * 4 + j2] = acc[i2][j2] + bias[n0 + tx * 4 + j2];
}

// ---------------- repack W_out rows to stride 1028 (16B-aligned float4 columns) ----------------
__global__ __launch_bounds__(256) void repack_wout(const float* __restrict__ W,
                                                   float* __restrict__ Wo) {
    const int k = blockIdx.x;
    for (int v = threadIdx.x; v < VP1; v += 256) Wo[k * WOS + v] = W[k * VP1 + v];
}

// ---------------- persistent per-batch-element decode: 1 WG per b ----------------
#define BD 576   // 9 waves: 4 logits, 5 gates
__global__ __launch_bounds__(BD, 1) void rnnt_decode(
    const float* __restrict__ xp, const float* __restrict__ Gm,
    const float* __restrict__ Wo, const float* __restrict__ Whh,
    const float* __restrict__ Wpred,
    const float* __restrict__ b_out, const float* __restrict__ b_lstm,
    const float* __restrict__ b_pred, const int* __restrict__ out_len,
    float* __restrict__ out) {
    __shared__ float f_s[Jn];
    __shared__ float h_s[Hn];
    __shared__ float c_s[Hn];
    __shared__ float g_s[G4n];
    __shared__ ull  pa_s[4];
    __shared__ int  tim_s[2], sym_s[2];

    const int b = blockIdx.x, tid = threadIdx.x;
    const int ol = out_len[b];
    const float* xpb = xp + b * Tn * Jn;

    // ---- prologue: h0,c0 from gates=b_lstm (h=c=0); dec0; f0 ----
    float dreg = 0.0f;   // cached dec value for this thread's column (tid<320)
    if (tid < Hn) {
        float c0 = sigmf(b_lstm[tid]) * tanhf(b_lstm[2 * Hn + tid]);
        float h0 = sigmf(b_lstm[3 * Hn + tid]) * tanhf(c0);
        h_s[tid] = h0; c_s[tid] = c0;
    }
    if (tid == 0) { tim_s[0] = 0; sym_s[0] = 0; }
    __syncthreads();
    if (tid < Jn) {
        float d = b_pred[tid];
#pragma unroll 8
        for (int k = 0; k < Hn; ++k) d += h_s[k] * Wpred[k * Jn + tid];
        dreg = d;
        float fv = xpb[tid] + d;             // t = 0
        f_s[tid] = fv > 0.0f ? fv : 0.0f;
    }
    __syncthreads();

    int lenacc = 0;
    for (int s = 0; s < Sn; ++s) {
        const int p = s & 1;
        const int told = tim_s[p], sold = sym_s[p];
        if (told >= ol) {
            // frozen: fill remaining outputs and quit
            if (tid == 0) {
                for (int ss = s; ss < Sn; ++ss) {
                    out[ss * Bn + b] = 1024.0f;
                    out[Sn * Bn + ss * Bn + b] = 0.0f;
                    out[2 * Sn * Bn + ss * Bn + b] = (float)told;
                }
            }
            break;
        }
        // ================= GEMV phase =================
        if (tid < 256) {
            // logits: cols 4t..4t+3 of padded W_out
            const int c0 = tid * 4;
            float4 acc = *(const float4*)(b_out + c0);
#pragma unroll 4
            for (int k = 0; k < Hn; k += 4) {
                float4 f4 = *(const float4*)(f_s + k);
                const float* wr = Wo + (size_t)k * WOS + c0;
                float4 w0 = *(const float4*)(wr);
                float4 w1 = *(const float4*)(wr + WOS);
                float4 w2 = *(const float4*)(wr + 2 * WOS);
                float4 w3 = *(const float4*)(wr + 3 * WOS);
                acc.x += f4.x * w0.x + f4.y * w1.x + f4.z * w2.x + f4.w * w3.x;
                acc.y += f4.x * w0.y + f4.y * w1.y + f4.z * w2.y + f4.w * w3.y;
                acc.z += f4.x * w0.z + f4.y * w1.z + f4.z * w2.z + f4.w * w3.z;
                acc.w += f4.x * w0.w + f4.y * w1.w + f4.z * w2.w + f4.w * w3.w;
            }
            ull key = pack_key(acc.x, c0);
            ull kk1 = pack_key(acc.y, c0 + 1); if (kk1 > key) key = kk1;
            ull kk2 = pack_key(acc.z, c0 + 2); if (kk2 > key) key = kk2;
            ull kk3 = pack_key(acc.w, c0 + 3); if (kk3 > key) key = kk3;
            if (tid < 64) {
                // wave 0 also owns column 1024 (5 k-terms per lane, sum-reduce)
                float p1024 = 0.0f;
#pragma unroll
                for (int r = 0; r < 5; ++r) {
                    int k = tid + 64 * r;
                    p1024 += f_s[k] * Wo[(size_t)k * WOS + 1024];
                }
#pragma unroll
                for (int m = 1; m < 64; m <<= 1) p1024 += __shfl_xor(p1024, m, 64);
                ull kb = pack_key(p1024 + b_out[Vn], Vn);
                if (kb > key) key = kb;
            }
#pragma unroll
            for (int m = 1; m < 64; m <<= 1) {
                ull o = __shfl_xor(key, m, 64);
                if (o > key) key = o;
            }
            if ((tid & 63) == 0) pa_s[tid >> 6] = key;
        } else {
            // gates: cols 4c..4c+3 of W_hh (h @ W_hh)
            const int ci = (tid - 256) * 4;
            float4 acc = make_float4(0.f, 0.f, 0.f, 0.f);
#pragma unroll 4
            for (int k = 0; k < Hn; k += 4) {
                float4 h4 = *(const float4*)(h_s + k);
                const float* wr = Whh + (size_t)k * G4n + ci;
                float4 w0 = *(const float4*)(wr);
                float4 w1 = *(const float4*)(wr + G4n);
                float4 w2 = *(const float4*)(wr + 2 * G4n);
                float4 w3 = *(const float4*)(wr + 3 * G4n);
                acc.x += h4.x * w0.x + h4.y * w1.x + h4.z * w2.x + h4.w * w3.x;
                acc.y += h4.x * w0.y + h4.y * w1.y + h4.z * w2.y + h4.w * w3.y;
                acc.z += h4.x * w0.z + h4.y * w1.z + h4.z * w2.z + h4.w * w3.z;
                acc.w += h4.x * w0.w + h4.y * w1.w + h4.z * w2.w + h4.w * w3.w;
            }
            *(float4*)(g_s + ci) = acc;
        }
        __syncthreads();   // (1) pa_s, g_s ready; h_s/f_s free to modify
        // ================= decode logic (uniform, all threads) =================
        ull key = pa_s[0];
        if (pa_s[1] > key) key = pa_s[1];
        if (pa_s[2] > key) key = pa_s[2];
        if (pa_s[3] > key) key = pa_s[3];
        const int label = key_idx(key);
        const bool emit = (label != Vn);             // told < ol guaranteed here
        int sym2 = emit ? sold + 1 : 0;
        const bool force = emit && (sym2 >= 2);
        const bool advance = (!emit) || force;
        const int tnew = told + (advance ? 1 : 0);
        sym2 = advance ? 0 : sym2;
        if (tid == 0) {
            out[s * Bn + b] = emit ? (float)label : 1024.0f;
            out[Sn * Bn + s * Bn + b] = key_val(key);
            out[2 * Sn * Bn + s * Bn + b] = (float)told;
            tim_s[p ^ 1] = tnew; sym_s[p ^ 1] = sym2;
            if (emit) lenacc++;
        }
        // ================= LSTM elementwise (emit only) =================
        if (emit && tid < Hn) {
            const float* gE = Gm + (size_t)label * G4n;
            float xi = g_s[tid]          + gE[tid];
            float xf = g_s[Hn + tid]     + gE[Hn + tid];
            float xg = g_s[2 * Hn + tid] + gE[2 * Hn + tid];
            float xo = g_s[3 * Hn + tid] + gE[3 * Hn + tid];
            float c2 = sigmf(xf) * c_s[tid] + sigmf(xi) * tanhf(xg);
            float h2 = sigmf(xo) * tanhf(c2);
            c_s[tid] = c2; h_s[tid] = h2;
        }
        __syncthreads();   // (2) h_s updated before dec GEMV reads all of it
        // ================= dec GEMV (emit only) + f refresh =================
        if (tid < Jn) {
            if (emit) {
                float d = b_pred[tid];
#pragma unroll 8
                for (int k = 0; k < Hn; ++k) d += h_s[k] * Wpred[k * Jn + tid];
                dreg = d;
            }
            const int tc = tnew < (Tn - 1) ? tnew : (Tn - 1);
            float fv = xpb[tc * Jn + tid] + dreg;
            f_s[tid] = fv > 0.0f ? fv : 0.0f;
        }
        __syncthreads();   // (3) f_s ready for next step
    }
    if (tid == 0) out[3 * Sn * Bn + b] = (float)lenacc;
}

extern "C" void kernel_launch(void* const* d_in, const int* in_sizes, int n_in,
                              void* d_out, int out_size, void* d_ws, size_t ws_size,
                              hipStream_t stream) {
    (void)in_sizes; (void)n_in; (void)out_size; (void)ws_size;
    const float* x      = (const float*)d_in[0];
    const int*   outlen = (const int*)d_in[1];
    const float* W_enc  = (const float*)d_in[2];
    const float* b_enc  = (const float*)d_in[3];
    const float* Emb    = (const float*)d_in[4];
    const float* W_ih   = (const float*)d_in[5];
    const float* W_hh   = (const float*)d_in[6];
    const float* b_lstm = (const float*)d_in[7];
    const float* W_pred = (const float*)d_in[8];
    const float* b_pred = (const float*)d_in[9];
    const float* W_out  = (const float*)d_in[10];
    const float* b_out  = (const float*)d_in[11];

    float* ws = (float*)d_ws;
    float* xp = ws + OFF_XP;
    float* Gm = ws + OFF_G;
    float* Wo = ws + OFF_WO;

    // x_proj = x @ W_enc + b_enc   (2048 x 320, K=1024)
    gemm_bias<<<dim3(5, 32), 256, 0, stream>>>(x, W_enc, b_enc, xp, Bn * Tn, Jn, 1024);
    // G = Emb @ W_ih + b_lstm      (1024 x 1280, K=320)
    gemm_bias<<<dim3(20, 16), 256, 0, stream>>>(Emb, W_ih, b_lstm, Gm, Vn, G4n, Hn);
    // padded W_out
    repack_wout<<<320, 256, 0, stream>>>(W_out, Wo);

    rnnt_decode<<<Bn, BD, 0, stream>>>(xp, Gm, Wo, W_hh, W_pred,
                                       b_out, b_lstm, b_pred, outlen, (float*)d_out);
}

// Round 5
// 2608.966 us; speedup vs baseline: 1.8144x; 1.5274x over previous
//
#include <hip/hip_runtime.h>
#include <math.h>

typedef unsigned long long ull;

constexpr int Bn = 32, Tn = 64, Hn = 320, Jn = 320, Vn = 1024, Sn = 128;
constexpr int G4n = 1280, VP1 = 1025;

// workspace layout (float units)
constexpr int OFF_XP  = 0;                       // 32*64*320
constexpr int OFF_G   = OFF_XP + Bn*Tn*Jn;       // 1024*1280
constexpr int OFF_WPT = OFF_G + Vn*G4n;          // 320*320
constexpr int OFF_F   = OFF_WPT + Jn*Hn;         // 32*320
constexpr int OFF_GG  = OFF_F + Bn*Jn;           // 32*1280
constexpr int OFF_KEY = OFF_GG + Bn*G4n;         // 32*32 ull = 2048 floats
constexpr int OFF_BAR = OFF_KEY + 2048;          // 32 arrival lines (32*32) + 32*8 flag lines (8192) = 9216 ints

#define AL(p)    __hip_atomic_load((p), __ATOMIC_RELAXED, __HIP_MEMORY_SCOPE_AGENT)
#define AS(p, v) __hip_atomic_store((p), (v), __ATOMIC_RELAXED, __HIP_MEMORY_SCOPE_AGENT)

__device__ __forceinline__ float sigmf(float x) { return 1.0f / (1.0f + expf(-x)); }

// monotonic (value,idx) pack: bigger float -> bigger key; tie -> smaller idx wins
__device__ __forceinline__ ull pack_key(float v, int idx) {
    unsigned u = __float_as_uint(v);
    u = (u & 0x80000000u) ? ~u : (u | 0x80000000u);
    return ((ull)u << 32) | (unsigned)(0x7FFFFFFF - idx);
}
__device__ __forceinline__ float key_val(ull k) {
    unsigned u = (unsigned)(k >> 32);
    return __uint_as_float((u & 0x80000000u) ? (u & 0x7FFFFFFFu) : ~u);
}
__device__ __forceinline__ int key_idx(ull k) { return 0x7FFFFFFF - (int)(k & 0xFFFFFFFFu); }

// ---- 8-WG group barrier: monotonic epochs, per-member flag-line fan-out ----
__device__ __forceinline__ void gbar8(int* arr, int* flg, int m, int epoch) {
    __syncthreads();   // drains vmcnt -> this WG's prior sc1 stores are globally visible
    int rw = 0;
    if (threadIdx.x == 0) {
        int old = __hip_atomic_fetch_add(arr, 1, __ATOMIC_RELAXED, __HIP_MEMORY_SCOPE_AGENT);
        rw = ((old & 7) == 7) ? 1 : 0;
    }
    if (threadIdx.x < 64) {
        rw = __shfl(rw, 0, 64);
        if (rw && threadIdx.x < 8) AS(flg + threadIdx.x * 32, epoch);
        if (threadIdx.x == 0) {
            while (AL(flg + m * 32) < epoch) __builtin_amdgcn_s_sleep(2);
        }
    }
    __syncthreads();
}

// ---------------- generic tiled f32 GEMM: C = A@B + bias ----------------
__global__ __launch_bounds__(256) void gemm_bias(const float* __restrict__ A,
                                                 const float* __restrict__ Bm,
                                                 const float* __restrict__ bias,
                                                 float* __restrict__ C,
                                                 int M, int N, int K) {
    __shared__ float As[16][65];
    __shared__ float Bs[16][65];
    const int tx = threadIdx.x & 15, ty = threadIdx.x >> 4;
    const int n0 = blockIdx.x * 64, m0 = blockIdx.y * 64;
    float acc[4][4] = {};
    for (int k0 = 0; k0 < K; k0 += 16) {
        for (int i = threadIdx.x; i < 1024; i += 256) {
            int mm = i >> 4, kk = i & 15;
            As[kk][mm] = A[(m0 + mm) * K + k0 + kk];
            int kk2 = i >> 6, nn = i & 63;
            Bs[kk2][nn] = Bm[(k0 + kk2) * N + n0 + nn];
        }
        __syncthreads();
#pragma unroll
        for (int kk = 0; kk < 16; ++kk) {
            float av[4], bv[4];
#pragma unroll
            for (int r = 0; r < 4; ++r) { av[r] = As[kk][ty * 4 + r]; bv[r] = Bs[kk][tx * 4 + r]; }
#pragma unroll
            for (int i2 = 0; i2 < 4; ++i2)
#pragma unroll
                for (int j2 = 0; j2 < 4; ++j2) acc[i2][j2] += av[i2] * bv[j2];
        }
        __syncthreads();
    }
#pragma unroll
    for (int i2 = 0; i2 < 4; ++i2)
#pragma unroll
        for (int j2 = 0; j2 < 4; ++j2)
            C[(m0 + ty * 4 + i2) * N + n0 + tx * 4 + j2] = acc[i2][j2] + bias[n0 + tx * 4 + j2];
}

// ---------------- 320x320 transpose: WpT[j][k] = W_pred[k][j] ----------------
__global__ __launch_bounds__(256) void transpose_pred(const float* __restrict__ W,
                                                      float* __restrict__ WT) {
    __shared__ float t[32][33];
    const int bx = blockIdx.x % 10, by = blockIdx.x / 10;
    const int lx = threadIdx.x & 31, ly = threadIdx.x >> 5;
#pragma unroll
    for (int r = 0; r < 32; r += 8)
        t[ly + r][lx] = W[(by * 32 + ly + r) * 320 + bx * 32 + lx];
    __syncthreads();
#pragma unroll
    for (int r = 0; r < 32; r += 8)
        WT[(bx * 32 + ly + r) * 320 + by * 32 + lx] = t[lx][ly + r];
}

// ---------------- decode: 8 WGs per batch element ----------------
__global__ __launch_bounds__(256, 1) void rnnt_decode(
    const float* __restrict__ xp, const float* __restrict__ Gm,
    const float* __restrict__ Wout, const float* __restrict__ Whh,
    const float* __restrict__ WpT, const float* __restrict__ Wpred,
    const float* __restrict__ b_out, const float* __restrict__ b_lstm,
    const float* __restrict__ b_pred, const int* __restrict__ out_len,
    float* __restrict__ fG, float* __restrict__ gG, ull* __restrict__ keyG,
    int* __restrict__ barG, float* __restrict__ out) {
    __shared__ ull fs8_[160];
    float* f_s = (float*)fs8_;
    __shared__ __align__(16) float h_s[Hn];
    __shared__ float c_s[Hn];
    __shared__ float dec_s[40];

    const int w = blockIdx.x, tid = threadIdx.x;
    const int b = w & 31, m = w >> 5;
    const int ol = out_len[b];
    const float* xpb = xp + b * Tn * Jn;
    float* fgl = fG + b * Jn;
    ull*   fgl8 = (ull*)fgl;
    float* gg = gG + b * G4n;
    ull*   keysb = keyG + b * 32;
    int*   arr = barG + b * 32;
    int*   flg = barG + 1024 + b * 8 * 32;

    // ---- prologue (fully replicated per member): h0, c0, dec0, f0 ----
    for (int r = tid; r < Hn; r += 256) {
        float c0 = sigmf(b_lstm[r]) * tanhf(b_lstm[2 * Hn + r]);
        float h0 = sigmf(b_lstm[3 * Hn + r]) * tanhf(c0);
        c_s[r] = c0; h_s[r] = h0;
    }
    __syncthreads();
    for (int c = tid; c < Jn; c += 256) {
        float d = b_pred[c];
        const float* wp = Wpred + c;
#pragma unroll 8
        for (int k = 0; k < Hn; ++k) d += h_s[k] * wp[k * Jn];
        float fv = xpb[c] + d;
        f_s[c] = fv > 0.0f ? fv : 0.0f;
        if (c >= m * 40 && c < m * 40 + 40) dec_s[c - m * 40] = d;
    }
    __syncthreads();

    int told = 0, sold = 0, lenacc = 0;
    bool hdirty = true;
    int s = 0;
    for (; s < Sn; ++s) {
        if (told >= ol) break;
        // ---- stage f from global (written by phase B of prev step) ----
        if (s > 0) {
            if (tid < 160) fs8_[tid] = AL(fgl8 + tid);
            __syncthreads();
        }
        // ================= Phase A =================
        if (tid < 128) {
            // logits: col c, 2-way k-split for ILP
            const int c = m * 128 + tid;
            const float* wp = Wout + c;
            float a0 = b_out[c], a1 = 0.0f;
#pragma unroll 8
            for (int k = 0; k < 160; ++k) {
                a0 += f_s[k] * wp[k * VP1];
                a1 += f_s[k + 160] * wp[(k + 160) * VP1];
            }
            ull key = pack_key(a0 + a1, c);
#pragma unroll
            for (int d = 1; d < 64; d <<= 1) {
                ull o = __shfl_xor(key, d, 64);
                if (o > key) key = o;
            }
            if ((tid & 63) == 0) AS(keysb + m * 2 + (tid >> 6), key);
        } else {
            const int u = tid - 128;
            if (hdirty) {
                for (int c0 = u; c0 < 160; c0 += 128) {
                    const int c = m * 160 + c0;
                    const float* wp = Whh + c;
                    float a0 = 0.0f, a1 = 0.0f;
#pragma unroll 8
                    for (int k = 0; k < 160; ++k) {
                        a0 += h_s[k] * wp[k * G4n];
                        a1 += h_s[k + 160] * wp[(k + 160) * G4n];
                    }
                    AS(gg + c, a0 + a1);
                }
            }
            if (m == 7 && u == 127) {
                // blank column 1024 (every step)
                const float* wp = Wout + Vn;
                float a0 = b_out[Vn], a1 = 0.0f;
#pragma unroll 8
                for (int k = 0; k < 160; ++k) {
                    a0 += f_s[k] * wp[k * VP1];
                    a1 += f_s[k + 160] * wp[(k + 160) * VP1];
                }
                AS(keysb + 16, pack_key(a0 + a1, Vn));
            }
        }
        gbar8(arr, flg, m, 2 * s + 1);
        // ================= Phase B (replicated decode) =================
        {
            const int lane = tid & 63;
            ull key = (lane < 17) ? AL(keysb + lane) : 0ull;
#pragma unroll
            for (int d = 1; d < 64; d <<= 1) {
                ull o = __shfl_xor(key, d, 64);
                if (o > key) key = o;
            }
            const int label = key_idx(key);
            const float mv = key_val(key);
            const bool emit = (label != Vn);
            int sym2 = emit ? sold + 1 : 0;
            const bool force = emit && (sym2 >= 2);
            const bool advance = (!emit) || force;
            const int tnew = told + (advance ? 1 : 0);
            sym2 = advance ? 0 : sym2;
            if (m == 0 && tid == 0) {
                out[s * Bn + b] = emit ? (float)label : 1024.0f;
                out[Sn * Bn + s * Bn + b] = mv;
                out[2 * Sn * Bn + s * Bn + b] = (float)told;
                if (emit) lenacc++;
            }
            if (emit) {
                const float* gE = Gm + (size_t)label * G4n;
                for (int r = tid; r < Hn; r += 256) {
                    float xi = AL(gg + r) + gE[r];
                    float xf = AL(gg + Hn + r) + gE[Hn + r];
                    float xg = AL(gg + 2 * Hn + r) + gE[2 * Hn + r];
                    float xo = AL(gg + 3 * Hn + r) + gE[3 * Hn + r];
                    float c2 = sigmf(xf) * c_s[r] + sigmf(xi) * tanhf(xg);
                    float h2 = sigmf(xo) * tanhf(c2);
                    c_s[r] = c2; h_s[r] = h2;
                }
            }
            __syncthreads();    // h_s complete before dec GEMV
            if (emit && tid < 160) {
                const int sc = tid >> 2, kk = tid & 3;
                const float* wr = WpT + (size_t)(m * 40 + sc) * Hn + kk * 80;
                const float4* h4 = (const float4*)(h_s + kk * 80);
                float4 dv = make_float4(0.f, 0.f, 0.f, 0.f);
#pragma unroll 5
                for (int q = 0; q < 20; ++q) {
                    float4 wv = ((const float4*)wr)[q];
                    float4 hv = h4[q];
                    dv.x += wv.x * hv.x; dv.y += wv.y * hv.y;
                    dv.z += wv.z * hv.z; dv.w += wv.w * hv.w;
                }
                float d = dv.x + dv.y + dv.z + dv.w;
                d += __shfl_xor(d, 1, 64);
                d += __shfl_xor(d, 2, 64);
                if (kk == 0) dec_s[sc] = d + b_pred[m * 40 + sc];
            }
            __syncthreads();    // dec_s ready
            if (tid < 40) {
                const int c = m * 40 + tid;
                const int tc = tnew < (Tn - 1) ? tnew : (Tn - 1);
                float fv = xpb[tc * Jn + c] + dec_s[tid];
                AS(fgl + c, fv > 0.0f ? fv : 0.0f);
            }
            hdirty = emit;
            told = tnew; sold = sym2;
        }
        gbar8(arr, flg, m, 2 * s + 2);
    }
    // tail fill + lengths (member 0 only)
    if (m == 0 && tid == 0) {
        for (int ss = s; ss < Sn; ++ss) {
            out[ss * Bn + b] = 1024.0f;
            out[Sn * Bn + ss * Bn + b] = 0.0f;
            out[2 * Sn * Bn + ss * Bn + b] = (float)told;
        }
        out[3 * Sn * Bn + b] = (float)lenacc;
    }
}

extern "C" void kernel_launch(void* const* d_in, const int* in_sizes, int n_in,
                              void* d_out, int out_size, void* d_ws, size_t ws_size,
                              hipStream_t stream) {
    (void)in_sizes; (void)n_in; (void)out_size; (void)ws_size;
    const float* x      = (const float*)d_in[0];
    const int*   outlen = (const int*)d_in[1];
    const float* W_enc  = (const float*)d_in[2];
    const float* b_enc  = (const float*)d_in[3];
    const float* Emb    = (const float*)d_in[4];
    const float* W_ih   = (const float*)d_in[5];
    const float* W_hh   = (const float*)d_in[6];
    const float* b_lstm = (const float*)d_in[7];
    const float* W_pred = (const float*)d_in[8];
    const float* b_pred = (const float*)d_in[9];
    const float* W_out  = (const float*)d_in[10];
    const float* b_out  = (const float*)d_in[11];

    float* ws  = (float*)d_ws;
    float* xp  = ws + OFF_XP;
    float* Gm  = ws + OFF_G;
    float* WpT = ws + OFF_WPT;
    float* fG  = ws + OFF_F;
    float* gG  = ws + OFF_GG;
    ull*   keyG = (ull*)(ws + OFF_KEY);
    int*   barG = (int*)(ws + OFF_BAR);

    hipMemsetAsync(barG, 0, 9216 * sizeof(int), stream);

    // x_proj = x @ W_enc + b_enc   (2048 x 320, K=1024)
    gemm_bias<<<dim3(5, 32), 256, 0, stream>>>(x, W_enc, b_enc, xp, Bn * Tn, Jn, 1024);
    // G = Emb @ W_ih + b_lstm      (1024 x 1280, K=320)
    gemm_bias<<<dim3(20, 16), 256, 0, stream>>>(Emb, W_ih, b_lstm, Gm, Vn, G4n, Hn);
    // W_pred transpose for the dec GEMV
    transpose_pred<<<100, 256, 0, stream>>>(W_pred, WpT);

    rnnt_decode<<<256, 256, 0, stream>>>(xp, Gm, W_out, W_hh, WpT, W_pred,
                                         b_out, b_lstm, b_pred, outlen,
                                         fG, gG, keyG, barG, (float*)d_out);
}

// Round 6
// 2470.788 us; speedup vs baseline: 1.9158x; 1.0559x over previous
//
#include <hip/hip_runtime.h>
#include <math.h>

typedef unsigned long long ull;

constexpr int Bn = 32, Tn = 64, Hn = 320, Jn = 320, Vn = 1024, Sn = 128;
constexpr int G4n = 1280, VP1 = 1025;

// workspace layout (float units)  -- total ~8.68 MB (<= proven R1-R3 footprint class)
constexpr int OFF_XP  = 0;                       // 32*64*320
constexpr int OFF_G   = OFF_XP + Bn*Tn*Jn;       // 1024*1280
constexpr int OFF_WPT = OFF_G + Vn*G4n;          // 320*320
constexpr int OFF_F   = OFF_WPT + Jn*Hn;         // 32*320
constexpr int OFF_GG  = OFF_F + Bn*Jn;           // 2*32*1280
constexpr int OFF_KEY = OFF_GG + 2*Bn*G4n;       // 32 groups * 32 ull = 2048 floats
constexpr int OFF_FLG = OFF_KEY + 2048;          // 32*8*32 ints

#define AL(p)    __hip_atomic_load((p), __ATOMIC_RELAXED, __HIP_MEMORY_SCOPE_AGENT)
#define AS(p, v) __hip_atomic_store((p), (v), __ATOMIC_RELAXED, __HIP_MEMORY_SCOPE_AGENT)

__device__ __forceinline__ float sigmf(float x) { return 1.0f / (1.0f + expf(-x)); }

// key = mapped_val(32) | epoch(21 bits, [31:11]) | (2047-idx)(11 bits)
// same-epoch keys order by (val, then smaller idx).  idx in [0,1024].
__device__ __forceinline__ ull pack_key_e(float v, int idx, int es) {
    unsigned u = __float_as_uint(v);
    u = (u & 0x80000000u) ? ~u : (u | 0x80000000u);
    return ((ull)u << 32) | ((ull)(unsigned)es << 11) | (unsigned)(2047 - idx);
}
__device__ __forceinline__ float key_val_e(ull k) {
    unsigned u = (unsigned)(k >> 32);
    return __uint_as_float((u & 0x80000000u) ? (u & 0x7FFFFFFFu) : ~u);
}
__device__ __forceinline__ int key_idx_e(ull k) { return 2047 - (int)(k & 0x7FF); }
__device__ __forceinline__ int key_ep_e(ull k)  { return (int)((k >> 11) & 0x1FFFFF); }

// ---------------- generic tiled f32 GEMM: C = A@B + bias ----------------
__global__ __launch_bounds__(256) void gemm_bias(const float* __restrict__ A,
                                                 const float* __restrict__ Bm,
                                                 const float* __restrict__ bias,
                                                 float* __restrict__ C,
                                                 int M, int N, int K) {
    __shared__ float As[16][65];
    __shared__ float Bs[16][65];
    const int tx = threadIdx.x & 15, ty = threadIdx.x >> 4;
    const int n0 = blockIdx.x * 64, m0 = blockIdx.y * 64;
    float acc[4][4] = {};
    for (int k0 = 0; k0 < K; k0 += 16) {
        for (int i = threadIdx.x; i < 1024; i += 256) {
            int mm = i >> 4, kk = i & 15;
            As[kk][mm] = A[(m0 + mm) * K + k0 + kk];
            int kk2 = i >> 6, nn = i & 63;
            Bs[kk2][nn] = Bm[(k0 + kk2) * N + n0 + nn];
        }
        __syncthreads();
#pragma unroll
        for (int kk = 0; kk < 16; ++kk) {
            float av[4], bv[4];
#pragma unroll
            for (int r = 0; r < 4; ++r) { av[r] = As[kk][ty * 4 + r]; bv[r] = Bs[kk][tx * 4 + r]; }
#pragma unroll
            for (int i2 = 0; i2 < 4; ++i2)
#pragma unroll
                for (int j2 = 0; j2 < 4; ++j2) acc[i2][j2] += av[i2] * bv[j2];
        }
        __syncthreads();
    }
#pragma unroll
    for (int i2 = 0; i2 < 4; ++i2)
#pragma unroll
        for (int j2 = 0; j2 < 4; ++j2)
            C[(m0 + ty * 4 + i2) * N + n0 + tx * 4 + j2] = acc[i2][j2] + bias[n0 + tx * 4 + j2];
}

// ---------------- 320x320 transpose: WpT[j][k] = W_pred[k][j] ----------------
__global__ __launch_bounds__(256) void transpose_pred(const float* __restrict__ W,
                                                      float* __restrict__ WT) {
    __shared__ float t[32][33];
    const int bx = blockIdx.x % 10, by = blockIdx.x / 10;
    const int lx = threadIdx.x & 31, ly = threadIdx.x >> 5;
#pragma unroll
    for (int r = 0; r < 32; r += 8)
        t[ly + r][lx] = W[(by * 32 + ly + r) * 320 + bx * 32 + lx];
    __syncthreads();
#pragma unroll
    for (int r = 0; r < 32; r += 8)
        WT[(bx * 32 + ly + r) * 320 + by * 32 + lx] = t[lx][ly + r];
}

// ---------------- decode: 8 WGs per batch element, barrier-free dataflow ----------------
__global__ __launch_bounds__(256, 1) void rnnt_decode(
    const float* __restrict__ xp, const float* __restrict__ Gm,
    const float* __restrict__ Wout, const float* __restrict__ Whh,
    const float* __restrict__ WpT, const float* __restrict__ Wpred,
    const float* __restrict__ b_out, const float* __restrict__ b_lstm,
    const float* __restrict__ b_pred, const int* __restrict__ out_len,
    float* __restrict__ fG, float* __restrict__ gG, ull* __restrict__ keyG,
    int* __restrict__ flgG, float* __restrict__ out) {
    __shared__ ull fs8_[160];
    float* f_s = (float*)fs8_;
    __shared__ __align__(16) float h_s[Hn];
    __shared__ float c_s[Hn];
    __shared__ float dec_s[40];
    __shared__ ull bk_s;

    const int w = blockIdx.x, tid = threadIdx.x;
    const int b = w & 31, m = w >> 5;
    const int ol = out_len[b];
    const float* xpb = xp + b * Tn * Jn;
    float* fgl = fG + b * Jn;
    ull*   fgl8 = (ull*)fgl;
    ull*   keysb = keyG + b * 32;
    int*   flgb = flgG + b * 256;          // 8 members x 32-int lines

    // ---- prologue (replicated): h0, c0, full dec0 -> f0; own dec slice cached ----
    for (int r = tid; r < Hn; r += 256) {
        float c0 = sigmf(b_lstm[r]) * tanhf(b_lstm[2 * Hn + r]);
        float h0 = sigmf(b_lstm[3 * Hn + r]) * tanhf(c0);
        c_s[r] = c0; h_s[r] = h0;
    }
    __syncthreads();
    for (int c = tid; c < Jn; c += 256) {
        const float* wp = Wpred + c;
        float d0 = 0.0f, d1 = 0.0f;
#pragma unroll 8
        for (int k = 0; k < 160; ++k) {
            d0 += h_s[k] * wp[k * Jn];
            d1 += h_s[k + 160] * wp[(k + 160) * Jn];
        }
        float d = b_pred[c] + d0 + d1;
        float fv = xpb[c] + d;
        f_s[c] = fv > 0.0f ? fv : 0.0f;
        int lc = c - m * 40;
        if (lc >= 0 && lc < 40) dec_s[lc] = d;
    }
    __syncthreads();

    int told = 0, sold = 0, lenacc = 0, lastq = 1;
    bool hdirty = true;
    int s = 0;
    for (; s < Sn; ++s) {
        if (told >= ol) break;
        const int es = s + 1;
        // ---- A1: gates GEMV from local h_s (only when h changed) ----
        if (hdirty) {
            lastq ^= 1;
            float* gq = gG + (size_t)(lastq * Bn + b) * G4n;
            int ci = (tid >= 128) ? (tid - 128) : (tid < 32 ? 128 + tid : -1);
            if (ci >= 0) {
                const int c = m * 160 + ci;
                const float* wp = Whh + c;
                float a0 = 0.0f, a1 = 0.0f;
#pragma unroll 8
                for (int k = 0; k < 160; ++k) {
                    a0 += h_s[k] * wp[k * G4n];
                    a1 += h_s[k + 160] * wp[(k + 160) * G4n];
                }
                AS(gq + c, a0 + a1);
            }
        }
        // ---- A2: f propagation (poll flags >= s, then load f) ----
        if (s > 0) {
            if (tid < 8) {
                while (AL(flgb + tid * 32) < s) __builtin_amdgcn_s_sleep(1);
            }
            __syncthreads();
            if (tid < 160) fs8_[tid] = AL(fgl8 + tid);
        }
        __syncthreads();   // drains ALL waves' gg stores (vmcnt(0) before s_barrier)
        // ---- A3: logits GEMV + epoch-tagged key store ----
        if (m == 7 && tid >= 192) {
            const int l = tid - 192;
            float p = 0.0f;
#pragma unroll
            for (int r = 0; r < 5; ++r) p += f_s[l + 64 * r] * Wout[(l + 64 * r) * VP1 + Vn];
#pragma unroll
            for (int d = 1; d < 64; d <<= 1) p += __shfl_xor(p, d, 64);
            if (l == 0) AS(keysb + 16, pack_key_e(p + b_out[Vn], Vn, es));
        }
        if (tid < 128) {
            const int c = m * 128 + tid;
            const float* wp = Wout + c;
            float a0 = b_out[c], a1 = 0.0f;
#pragma unroll 8
            for (int k = 0; k < 160; ++k) {
                a0 += f_s[k] * wp[k * VP1];
                a1 += f_s[k + 160] * wp[(k + 160) * VP1];
            }
            ull key = pack_key_e(a0 + a1, c, es);
#pragma unroll
            for (int d = 1; d < 64; d <<= 1) {
                ull o = __shfl_xor(key, d, 64);
                if (o > key) key = o;
            }
            if ((tid & 63) == 0) AS(keysb + m * 2 + (tid >> 6), key);
        }
        // ---- B: poll 17 keys (wave0), reduce, broadcast ----
        if (tid < 64) {
            ull k = 0;
            if (tid < 17) {
                do { k = AL(keysb + tid); if (key_ep_e(k) >= es) break;
                     __builtin_amdgcn_s_sleep(1); } while (true);
            }
#pragma unroll
            for (int d = 1; d < 64; d <<= 1) {
                ull o = __shfl_xor(k, d, 64);
                if (o > k) k = o;
            }
            if (tid == 0) bk_s = k;
        }
        __syncthreads();
        const ull bk = bk_s;
        const int label = key_idx_e(bk);
        const bool emit = (label != Vn);
        int sym2 = emit ? sold + 1 : 0;
        const bool force = emit && (sym2 >= 2);
        const bool advance = (!emit) || force;
        const int tnew = told + (advance ? 1 : 0);
        sym2 = advance ? 0 : sym2;
        if (m == 0 && tid == 0) {
            out[s * Bn + b] = emit ? (float)label : 1024.0f;
            out[Sn * Bn + s * Bn + b] = key_val_e(bk);
            out[2 * Sn * Bn + s * Bn + b] = (float)told;
            if (emit) lenacc++;
        }
        // ---- LSTM elementwise (replicated) ----
        if (emit) {
            const float* gq = gG + (size_t)(lastq * Bn + b) * G4n;
            const float* gE = Gm + (size_t)label * G4n;
            for (int r = tid; r < Hn; r += 256) {
                float xi = AL(gq + r) + gE[r];
                float xf = AL(gq + Hn + r) + gE[Hn + r];
                float xg = AL(gq + 2 * Hn + r) + gE[2 * Hn + r];
                float xo = AL(gq + 3 * Hn + r) + gE[3 * Hn + r];
                float c2 = sigmf(xf) * c_s[r] + sigmf(xi) * tanhf(xg);
                float h2 = sigmf(xo) * tanhf(c2);
                c_s[r] = c2; h_s[r] = h2;
            }
        }
        __syncthreads();   // h_s complete
        // ---- dec GEMV (own 40 cols, emit only) ----
        if (emit && tid < 160) {
            const int sc = tid >> 2, kk = tid & 3;
            const float* wr = WpT + (size_t)(m * 40 + sc) * Hn + kk * 80;
            const float4* h4 = (const float4*)(h_s + kk * 80);
            float4 dv = make_float4(0.f, 0.f, 0.f, 0.f);
#pragma unroll 5
            for (int q = 0; q < 20; ++q) {
                float4 wv = ((const float4*)wr)[q];
                float4 hv = h4[q];
                dv.x += wv.x * hv.x; dv.y += wv.y * hv.y;
                dv.z += wv.z * hv.z; dv.w += wv.w * hv.w;
            }
            float d = dv.x + dv.y + dv.z + dv.w;
            d += __shfl_xor(d, 1, 64);
            d += __shfl_xor(d, 2, 64);
            if (kk == 0) dec_s[sc] = d + b_pred[m * 40 + sc];
        }
        __syncthreads();   // dec_s ready
        // ---- f slice write + release flag ----
        if (tid < 20) {
            const int c0 = m * 40 + 2 * tid;
            const int tc = tnew < (Tn - 1) ? tnew : (Tn - 1);
            float f0v = xpb[tc * Jn + c0] + dec_s[2 * tid];
            float f1v = xpb[tc * Jn + c0 + 1] + dec_s[2 * tid + 1];
            union { float f2[2]; ull u; } pk;
            pk.f2[0] = f0v > 0.0f ? f0v : 0.0f;
            pk.f2[1] = f1v > 0.0f ? f1v : 0.0f;
            AS(fgl8 + m * 20 + tid, pk.u);
        }
        asm volatile("s_waitcnt vmcnt(0)" ::: "memory");
        if (tid == 0) AS(flgb + m * 32, es);
        hdirty = emit; told = tnew; sold = sym2;
    }
    // tail fill + lengths (member 0; all its threads exited at same s)
    if (m == 0) {
        for (int ss = s + tid; ss < Sn; ss += 256) {
            out[ss * Bn + b] = 1024.0f;
            out[Sn * Bn + ss * Bn + b] = 0.0f;
            out[2 * Sn * Bn + ss * Bn + b] = (float)told;
        }
        if (tid == 0) out[3 * Sn * Bn + b] = (float)lenacc;
    }
}

extern "C" void kernel_launch(void* const* d_in, const int* in_sizes, int n_in,
                              void* d_out, int out_size, void* d_ws, size_t ws_size,
                              hipStream_t stream) {
    (void)in_sizes; (void)n_in; (void)out_size; (void)ws_size;
    const float* x      = (const float*)d_in[0];
    const int*   outlen = (const int*)d_in[1];
    const float* W_enc  = (const float*)d_in[2];
    const float* b_enc  = (const float*)d_in[3];
    const float* Emb    = (const float*)d_in[4];
    const float* W_ih   = (const float*)d_in[5];
    const float* W_hh   = (const float*)d_in[6];
    const float* b_lstm = (const float*)d_in[7];
    const float* W_pred = (const float*)d_in[8];
    const float* b_pred = (const float*)d_in[9];
    const float* W_out  = (const float*)d_in[10];
    const float* b_out  = (const float*)d_in[11];

    float* ws   = (float*)d_ws;
    float* xp   = ws + OFF_XP;
    float* Gm   = ws + OFF_G;
    float* WpT  = ws + OFF_WPT;
    float* fG   = ws + OFF_F;
    float* gG   = ws + OFF_GG;
    ull*   keyG = (ull*)(ws + OFF_KEY);
    int*   flgG = (int*)(ws + OFF_FLG);

    // reset epoch state (keys + flags) every launch/replay
    hipMemsetAsync(keyG, 0, 2048 * 4 + 8192 * 4, stream);

    gemm_bias<<<dim3(5, 32), 256, 0, stream>>>(x, W_enc, b_enc, xp, Bn * Tn, Jn, 1024);
    gemm_bias<<<dim3(20, 16), 256, 0, stream>>>(Emb, W_ih, b_lstm, Gm, Vn, G4n, Hn);
    transpose_pred<<<100, 256, 0, stream>>>(W_pred, WpT);

    rnnt_decode<<<256, 256, 0, stream>>>(xp, Gm, W_out, W_hh, WpT, W_pred,
                                         b_out, b_lstm, b_pred, outlen,
                                         fG, gG, keyG, flgG, (float*)d_out);
}

// Round 8
// 2410.054 us; speedup vs baseline: 1.9641x; 1.0252x over previous
//
#include <hip/hip_runtime.h>
#include <math.h>

typedef unsigned long long ull;

constexpr int Bn = 32, Tn = 64, Hn = 320, Jn = 320, Vn = 1024, Sn = 128;
constexpr int G4n = 1280, VP1 = 1025, WO4S = 1028;  // WO4S: padded col count in repacked W_out

// workspace layout (float units) -- ~11.6 MB total
constexpr int OFF_XP  = 0;                        // 32*64*320      = 655360
constexpr int OFF_G   = OFF_XP + Bn*Tn*Jn;        // 1024*1280     = 1310720
constexpr int OFF_WPT = OFF_G + Vn*G4n;           // 320*320       = 102400
constexpr int OFF_WO4 = OFF_WPT + Jn*Hn;          // 80*1028*4     = 328960
constexpr int OFF_WH4 = OFF_WO4 + 80*WO4S*4;      // 80*1280*4     = 409600
constexpr int OFF_F   = OFF_WH4 + 80*G4n*4;       // 32*320
constexpr int OFF_GG  = OFF_F + Bn*Jn;            // 2*32*1280
constexpr int OFF_KEY = OFF_GG + 2*Bn*G4n;        // 32 groups * 32 ull = 2048 f32
constexpr int OFF_FFL = OFF_KEY + 2048;           // 32*32 ints (f-ready flags)
constexpr int OFF_GGF = OFF_FFL + 1024;           // 32*32 ints (gg-ready flags)

#define AL(p)    __hip_atomic_load((p), __ATOMIC_RELAXED, __HIP_MEMORY_SCOPE_AGENT)
#define AS(p, v) __hip_atomic_store((p), (v), __ATOMIC_RELAXED, __HIP_MEMORY_SCOPE_AGENT)

__device__ __forceinline__ float sigmf(float x) { return 1.0f / (1.0f + expf(-x)); }

// key = mapped_val(32) | epoch(21 bits) | (2047-idx)(11 bits)
__device__ __forceinline__ ull pack_key_e(float v, int idx, int es) {
    unsigned u = __float_as_uint(v);
    u = (u & 0x80000000u) ? ~u : (u | 0x80000000u);
    return ((ull)u << 32) | ((ull)(unsigned)es << 11) | (unsigned)(2047 - idx);
}
__device__ __forceinline__ float key_val_e(ull k) {
    unsigned u = (unsigned)(k >> 32);
    return __uint_as_float((u & 0x80000000u) ? (u & 0x7FFFFFFFu) : ~u);
}
__device__ __forceinline__ int key_idx_e(ull k) { return 2047 - (int)(k & 0x7FF); }
__device__ __forceinline__ int key_ep_e(ull k)  { return (int)((k >> 11) & 0x1FFFFF); }

// ---------------- generic tiled f32 GEMM: C = A@B + bias ----------------
__global__ __launch_bounds__(256) void gemm_bias(const float* __restrict__ A,
                                                 const float* __restrict__ Bm,
                                                 const float* __restrict__ bias,
                                                 float* __restrict__ C,
                                                 int M, int N, int K) {
    __shared__ float As[16][65];
    __shared__ float Bs[16][65];
    const int tx = threadIdx.x & 15, ty = threadIdx.x >> 4;
    const int n0 = blockIdx.x * 64, m0 = blockIdx.y * 64;
    float acc[4][4] = {};
    for (int k0 = 0; k0 < K; k0 += 16) {
        for (int i = threadIdx.x; i < 1024; i += 256) {
            int mm = i >> 4, kk = i & 15;
            As[kk][mm] = A[(m0 + mm) * K + k0 + kk];
            int kk2 = i >> 6, nn = i & 63;
            Bs[kk2][nn] = Bm[(k0 + kk2) * N + n0 + nn];
        }
        __syncthreads();
#pragma unroll
        for (int kk = 0; kk < 16; ++kk) {
            float av[4], bv[4];
#pragma unroll
            for (int r = 0; r < 4; ++r) { av[r] = As[kk][ty * 4 + r]; bv[r] = Bs[kk][tx * 4 + r]; }
#pragma unroll
            for (int i2 = 0; i2 < 4; ++i2)
#pragma unroll
                for (int j2 = 0; j2 < 4; ++j2) acc[i2][j2] += av[i2] * bv[j2];
        }
        __syncthreads();
    }
#pragma unroll
    for (int i2 = 0; i2 < 4; ++i2)
#pragma unroll
        for (int j2 = 0; j2 < 4; ++j2)
            C[(m0 + ty * 4 + i2) * N + n0 + tx * 4 + j2] = acc[i2][j2] + bias[n0 + tx * 4 + j2];
}

// ---------------- 320x320 transpose ----------------
__global__ __launch_bounds__(256) void transpose_pred(const float* __restrict__ W,
                                                      float* __restrict__ WT) {
    __shared__ float t[32][33];
    const int bx = blockIdx.x % 10, by = blockIdx.x / 10;
    const int lx = threadIdx.x & 31, ly = threadIdx.x >> 5;
#pragma unroll
    for (int r = 0; r < 32; r += 8)
        t[ly + r][lx] = W[(by * 32 + ly + r) * 320 + bx * 32 + lx];
    __syncthreads();
#pragma unroll
    for (int r = 0; r < 32; r += 8)
        WT[(bx * 32 + ly + r) * 320 + by * 32 + lx] = t[lx][ly + r];
}

// ---------------- k4-interleave repacks: W4[k/4][col][4] = W[k][col] ----------------
__global__ __launch_bounds__(256) void repack_wout4(const float* __restrict__ W,
                                                    float* __restrict__ W4) {
    const int k4 = blockIdx.x;
    for (int c = threadIdx.x; c < VP1; c += 256) {
        float4 v;
        v.x = W[(k4 * 4 + 0) * VP1 + c];
        v.y = W[(k4 * 4 + 1) * VP1 + c];
        v.z = W[(k4 * 4 + 2) * VP1 + c];
        v.w = W[(k4 * 4 + 3) * VP1 + c];
        ((float4*)W4)[(size_t)k4 * WO4S + c] = v;
    }
}
__global__ __launch_bounds__(256) void repack_whh4(const float* __restrict__ W,
                                                   float* __restrict__ W4) {
    const int k4 = blockIdx.x;
    for (int c = threadIdx.x; c < G4n; c += 256) {
        float4 v;
        v.x = W[(k4 * 4 + 0) * G4n + c];
        v.y = W[(k4 * 4 + 1) * G4n + c];
        v.z = W[(k4 * 4 + 2) * G4n + c];
        v.w = W[(k4 * 4 + 3) * G4n + c];
        ((float4*)W4)[(size_t)k4 * G4n + c] = v;
    }
}

// ---------------- decode: 8 WGs per batch element, barrier-free dataflow ----------------
__global__ __launch_bounds__(256, 1) void rnnt_decode(
    const float* __restrict__ xp, const float* __restrict__ Gm,
    const float* __restrict__ Wo4, const float* __restrict__ Wh4,
    const float* __restrict__ WpT, const float* __restrict__ Wpred,
    const float* __restrict__ b_out, const float* __restrict__ b_lstm,
    const float* __restrict__ b_pred, const int* __restrict__ out_len,
    float* __restrict__ fG, float* __restrict__ gG, ull* __restrict__ keyG,
    int* __restrict__ flgG, float* __restrict__ out) {
    __shared__ __align__(16) ull fs8_[160];
    float* f_s = (float*)fs8_;
    __shared__ __align__(16) float h_s[Hn];
    __shared__ float c_s[Hn];
    __shared__ float dec_s[40];
    __shared__ ull bk_s;

    const int w = blockIdx.x, tid = threadIdx.x;
    const int b = w & 31, m = w >> 5;
    const int ol = out_len[b];
    const float* xpb = xp + b * Tn * Jn;
    float* fgl = fG + b * Jn;
    ull*   fgl8 = (ull*)fgl;
    ull*   keysb = keyG + b * 32;
    int*   flgb = flgG + b * 32;          // f-ready flags (8 members)
    int*   ggfb = flgG + 1024 + b * 32;   // gg-ready flags (16)

    const float4* Wo4f = (const float4*)Wo4;
    const float4* Wh4f = (const float4*)Wh4;

    // ---- prologue (replicated): h0, c0, full dec0 -> f0; own dec slice cached ----
    for (int r = tid; r < Hn; r += 256) {
        float c0 = sigmf(b_lstm[r]) * tanhf(b_lstm[2 * Hn + r]);
        float h0 = sigmf(b_lstm[3 * Hn + r]) * tanhf(c0);
        c_s[r] = c0; h_s[r] = h0;
    }
    __syncthreads();
    for (int c = tid; c < Jn; c += 256) {
        const float* wp = Wpred + c;
        float d0 = 0.0f, d1 = 0.0f;
#pragma unroll 8
        for (int k = 0; k < 160; ++k) {
            d0 += h_s[k] * wp[k * Jn];
            d1 += h_s[k + 160] * wp[(k + 160) * Jn];
        }
        float d = b_pred[c] + d0 + d1;
        float fv = xpb[c] + d;
        f_s[c] = fv > 0.0f ? fv : 0.0f;
        int lc = c - m * 40;
        if (lc >= 0 && lc < 40) dec_s[lc] = d;
    }
    __syncthreads();

    int told = 0, sold = 0, lenacc = 0, lastq = 1;
    bool hdirty = true;
    int s = 0;
    for (; s < Sn; ++s) {
        if (told >= ol) break;
        const int es = s + 1;
        // ---- A1: gates GEMV from local h_s (only when h changed) ----
        if (hdirty) {
            lastq ^= 1;
            float* gq = gG + (size_t)(lastq * Bn + b) * G4n;
            const float4* h4 = (const float4*)h_s;
            int ci = (tid >= 128) ? (tid - 128) : (tid < 32 ? 128 + tid : -1);
            if (ci >= 0) {
                const int c = m * 160 + ci;
                const float4* w4 = Wh4f + c;
                float ax = 0.f, ay = 0.f, az = 0.f, aw = 0.f;
#pragma unroll 20
                for (int k4 = 0; k4 < 80; ++k4) {
                    float4 wv = w4[(size_t)k4 * G4n];
                    float4 hv = h4[k4];
                    ax += wv.x * hv.x; ay += wv.y * hv.y;
                    az += wv.z * hv.z; aw += wv.w * hv.w;
                }
                AS(gq + c, ax + ay + az + aw);
            }
            asm volatile("s_waitcnt vmcnt(0)" ::: "memory");
            if (tid == 128 || tid == 192)
                AS(ggfb + m * 2 + ((tid - 128) >> 6), es);
        }
        // ---- A2: f propagation (poll flags >= s, then load f) ----
        if (s > 0) {
            if (tid < 8) {
                while (AL(flgb + tid * 4) < s) __builtin_amdgcn_s_sleep(1);
            }
            __syncthreads();
            if (tid < 160) fs8_[tid] = AL(fgl8 + tid);
        }
        __syncthreads();   // f_s ready; gg stores drained (vmcnt(0) before s_barrier)
        // ---- A3 (m==7, wave 3): blank column 1024, spread over 64 lanes ----
        if (m == 7 && tid >= 192) {
            const int l = tid - 192;
            const float4* f4 = (const float4*)f_s;
            const float4* wb = Wo4f + Vn;
            float4 wv = wb[(size_t)l * WO4S];
            float4 fv = f4[l];
            float p = wv.x * fv.x + wv.y * fv.y + wv.z * fv.z + wv.w * fv.w;
            if (l < 16) {
                float4 wv2 = wb[(size_t)(64 + l) * WO4S];
                float4 fv2 = f4[64 + l];
                p += wv2.x * fv2.x + wv2.y * fv2.y + wv2.z * fv2.z + wv2.w * fv2.w;
            }
#pragma unroll
            for (int d = 1; d < 64; d <<= 1) p += __shfl_xor(p, d, 64);
            if (l == 0) AS(keysb + 16, pack_key_e(p + b_out[Vn], Vn, es));
        }
        // ---- A4: logits GEMV (128 cols, coalesced float4 weights) ----
        if (tid < 128) {
            const int c = m * 128 + tid;
            const float4* w4 = Wo4f + c;
            const float4* f4 = (const float4*)f_s;
            float ax = 0.f, ay = 0.f, az = 0.f, aw = 0.f;
#pragma unroll 20
            for (int k4 = 0; k4 < 80; ++k4) {
                float4 wv = w4[(size_t)k4 * WO4S];
                float4 fv = f4[k4];
                ax += wv.x * fv.x; ay += wv.y * fv.y;
                az += wv.z * fv.z; aw += wv.w * fv.w;
            }
            ull key = pack_key_e(ax + ay + az + aw + b_out[c], c, es);
#pragma unroll
            for (int d = 1; d < 64; d <<= 1) {
                ull o = __shfl_xor(key, d, 64);
                if (o > key) key = o;
            }
            if ((tid & 63) == 0) AS(keysb + m * 2 + (tid >> 6), key);
        }
        // ---- B: wave0 polls 17 keys (+16 gg flags when dirty), reduce ----
        if (tid < 64) {
            ull k = 0;
            if (tid < 17) {
                do {
                    k = AL(keysb + tid);
                    if (key_ep_e(k) >= es) break;
                    __builtin_amdgcn_s_sleep(1);
                } while (true);
            } else if (hdirty && tid < 33) {
                while (AL(ggfb + (tid - 17)) < es) __builtin_amdgcn_s_sleep(1);
            }
#pragma unroll
            for (int d = 1; d < 64; d <<= 1) {
                ull o = __shfl_xor(k, d, 64);
                if (o > k) k = o;
            }
            if (tid == 0) bk_s = k;
        }
        __syncthreads();
        const ull bk = bk_s;
        const int label = key_idx_e(bk);
        const bool emit = (label != Vn);
        int sym2 = emit ? sold + 1 : 0;
        const bool force = emit && (sym2 >= 2);
        const bool advance = (!emit) || force;
        const int tnew = told + (advance ? 1 : 0);
        sym2 = advance ? 0 : sym2;
        if (m == 0 && tid == 0) {
            out[s * Bn + b] = emit ? (float)label : 1024.0f;
            out[Sn * Bn + s * Bn + b] = key_val_e(bk);
            out[2 * Sn * Bn + s * Bn + b] = (float)told;
            if (emit) lenacc++;
        }
        // ---- LSTM elementwise (replicated) ----
        if (emit) {
            const float* gq = gG + (size_t)(lastq * Bn + b) * G4n;
            const float* gE = Gm + (size_t)label * G4n;
            for (int r = tid; r < Hn; r += 256) {
                float xi = AL(gq + r)          + gE[r];
                float xf = AL(gq + Hn + r)     + gE[Hn + r];
                float xg = AL(gq + 2 * Hn + r) + gE[2 * Hn + r];
                float xo = AL(gq + 3 * Hn + r) + gE[3 * Hn + r];
                float c2 = sigmf(xf) * c_s[r] + sigmf(xi) * tanhf(xg);
                float h2 = sigmf(xo) * tanhf(c2);
                c_s[r] = c2; h_s[r] = h2;
            }
        }
        __syncthreads();   // h_s complete
        // ---- dec GEMV (own 40 cols, emit only) ----
        if (emit && tid < 160) {
            const int sc = tid >> 2, kk = tid & 3;
            const float* wr = WpT + (size_t)(m * 40 + sc) * Hn + kk * 80;
            const float4* h4 = (const float4*)(h_s + kk * 80);
            float4 dv = make_float4(0.f, 0.f, 0.f, 0.f);
#pragma unroll 5
            for (int q = 0; q < 20; ++q) {
                float4 wv = ((const float4*)wr)[q];
                float4 hv = h4[q];
                dv.x += wv.x * hv.x; dv.y += wv.y * hv.y;
                dv.z += wv.z * hv.z; dv.w += wv.w * hv.w;
            }
            float d = dv.x + dv.y + dv.z + dv.w;
            d += __shfl_xor(d, 1, 64);
            d += __shfl_xor(d, 2, 64);
            if (kk == 0) dec_s[sc] = d + b_pred[m * 40 + sc];
        }
        __syncthreads();   // dec_s ready
        // ---- f slice write + release flag ----
        if (tid < 20) {
            const int c0l = 2 * tid;
            const int tc = tnew < (Tn - 1) ? tnew : (Tn - 1);
            float f0v = xpb[tc * Jn + m * 40 + c0l] + dec_s[c0l];
            float f1v = xpb[tc * Jn + m * 40 + c0l + 1] + dec_s[c0l + 1];
            union { float f2[2]; ull u; } pk;
            pk.f2[0] = f0v > 0.0f ? f0v : 0.0f;
            pk.f2[1] = f1v > 0.0f ? f1v : 0.0f;
            AS(fgl8 + m * 20 + tid, pk.u);
        }
        asm volatile("s_waitcnt vmcnt(0)" ::: "memory");
        if (tid == 0) AS(flgb + m * 4, es);
        hdirty = emit; told = tnew; sold = sym2;
    }
    // tail fill + lengths (member 0)
    if (m == 0) {
        for (int ss = s + tid; ss < Sn; ss += 256) {
            out[ss * Bn + b] = 1024.0f;
            out[Sn * Bn + ss * Bn + b] = 0.0f;
            out[2 * Sn * Bn + ss * Bn + b] = (float)told;
        }
        if (tid == 0) out[3 * Sn * Bn + b] = (float)lenacc;
    }
}

extern "C" void kernel_launch(void* const* d_in, const int* in_sizes, int n_in,
                              void* d_out, int out_size, void* d_ws, size_t ws_size,
                              hipStream_t stream) {
    (void)in_sizes; (void)n_in; (void)out_size; (void)ws_size;
    const float* x      = (const float*)d_in[0];
    const int*   outlen = (const int*)d_in[1];
    const float* W_enc  = (const float*)d_in[2];
    const float* b_enc  = (const float*)d_in[3];
    const float* Emb    = (const float*)d_in[4];
    const float* W_ih   = (const float*)d_in[5];
    const float* W_hh   = (const float*)d_in[6];
    const float* b_lstm = (const float*)d_in[7];
    const float* W_pred = (const float*)d_in[8];
    const float* b_pred = (const float*)d_in[9];
    const float* W_out  = (const float*)d_in[10];
    const float* b_out  = (const float*)d_in[11];

    float* ws   = (float*)d_ws;
    float* xp   = ws + OFF_XP;
    float* Gm   = ws + OFF_G;
    float* WpT  = ws + OFF_WPT;
    float* Wo4  = ws + OFF_WO4;
    float* Wh4  = ws + OFF_WH4;
    float* fG   = ws + OFF_F;
    float* gG   = ws + OFF_GG;
    ull*   keyG = (ull*)(ws + OFF_KEY);
    int*   flgG = (int*)(ws + OFF_FFL);

    // reset sync state (keys + f-flags + gg-flags) every launch/replay
    hipMemsetAsync(keyG, 0, (2048 + 1024 + 1024) * sizeof(float), stream);

    gemm_bias<<<dim3(5, 32), 256, 0, stream>>>(x, W_enc, b_enc, xp, Bn * Tn, Jn, 1024);
    gemm_bias<<<dim3(20, 16), 256, 0, stream>>>(Emb, W_ih, b_lstm, Gm, Vn, G4n, Hn);
    transpose_pred<<<100, 256, 0, stream>>>(W_pred, WpT);
    repack_wout4<<<80, 256, 0, stream>>>(W_out, Wo4);
    repack_whh4<<<80, 256, 0, stream>>>(W_hh, Wh4);

    rnnt_decode<<<256, 256, 0, stream>>>(xp, Gm, Wo4, Wh4, WpT, W_pred,
                                         b_out, b_lstm, b_pred, outlen,
                                         fG, gG, keyG, flgG, (float*)d_out);
}